// Round 3
// baseline (2382.420 us; speedup 1.0000x reference)
//
#include <hip/hip_runtime.h>

// GNNTEP R3: block-per-batch GEMMs with LDS-resident A (XOR-swizzled, 64KB),
// double-buffered 8KB B tiles via global_load_lds, W2 frags in registers.
// LDS = 80KB exactly -> 2 blocks/CU. X-transpose fused into gemm_ax staging.

typedef short  s16x8 __attribute__((ext_vector_type(8)));
typedef float  f32x4 __attribute__((ext_vector_type(4)));

#define NN   512
#define NB   1024
#define NH   64
#define LDT  72   // k_h1 LDS row stride

#define MFMA16(a, b, c) __builtin_amdgcn_mfma_f32_16x16x32_bf16((a), (b), (c), 0, 0, 0)

#define GLOAD16(g, l) __builtin_amdgcn_global_load_lds( \
    (const __attribute__((address_space(1))) unsigned*)(g), \
    (__attribute__((address_space(3))) unsigned*)(l), 16, 0, 0)

__device__ __forceinline__ unsigned short f2bf(float f) {
  union { float f; unsigned u; } v; v.f = f;
  unsigned r = v.u + 0x7fffu + ((v.u >> 16) & 1u);   // RNE
  return (unsigned short)(r >> 16);
}
__device__ __forceinline__ float bf2f(unsigned short h) {
  union { unsigned u; float f; } v; v.u = ((unsigned)h) << 16;
  return v.f;
}

// Stage one 64x64 bf16 B-tile (rows n0..n0+63, k-slice kt) into LDS with
// in-row 16B-slot XOR swizzle: LDS[n][slot] = G[n][slot ^ (n&7)].
__device__ __forceinline__ void stageB(unsigned short* buf, const unsigned short* __restrict__ src,
                                       int n0, int kt, int wid, int lane) {
#pragma unroll
  for (int q = 0; q < 2; ++q) {
    int g = wid * 2 + q;                    // 8-row group
    const unsigned short* gsrc = src + (size_t)(n0 + g * 8 + (lane >> 3)) * NN
                                     + kt * 64 + (((lane & 7) ^ (lane >> 3)) << 3);
    GLOAD16(gsrc, &buf[g * 512]);
  }
}

// ---------------- prep ----------------
__global__ void k_prep_adj(const float* __restrict__ adj, unsigned short* __restrict__ adjbf) {
  int idx = blockIdx.x * 256 + threadIdx.x;        // 512*512
  int n = idx >> 9, m = idx & 511;
  float v = adj[idx];
  if (n == m) v = 0.f;
  adjbf[idx] = f2bf(v);
}

// W1t[i][f][w] = W1[i][w][f];  W2t[i][d][f] = W2[i][f][d]
__global__ void k_prep_w(const float* __restrict__ W1, const float* __restrict__ W2,
                         unsigned short* __restrict__ W1t, unsigned short* __restrict__ W2t) {
  int idx = blockIdx.x * 256 + threadIdx.x;        // 3*64*64
  int i = idx >> 12, rc_ = idx & 4095;
  int src = (i << 12) + ((rc_ & 63) << 6) + (rc_ >> 6);
  W1t[idx] = f2bf(W1[src]);
  W2t[idx] = f2bf(W2[src]);
}

// ---------------- AX = adj @ X, block per b, A=X^T resident ----------------
__global__ __launch_bounds__(256)
void k_gemm_ax(const float* __restrict__ X, const unsigned short* __restrict__ adjbf,
               unsigned short* __restrict__ AX) {
  __shared__ unsigned short Ares[64 * 512];     // [w][m swz]
  __shared__ unsigned short Bt[2][64 * 64];
  int b = blockIdx.x, t = threadIdx.x, lane = t & 63, wid = t >> 6;
  int wi = wid >> 1, wj = wid & 1;
  // transpose-stage X[b] (f32 [512 m][64 w]) -> Ares[w][m] bf16, swizzled
  {
    const float* xb = X + (size_t)b * (NN * NH);
    int m0 = t * 2;
    const float4* r0 = (const float4*)(xb + (size_t)m0 * NH);
    const float4* r1 = (const float4*)(xb + (size_t)(m0 + 1) * NH);
#pragma unroll
    for (int j = 0; j < 16; ++j) {
      float4 v0 = r0[j], v1 = r1[j];
      float e0[4] = {v0.x, v0.y, v0.z, v0.w};
      float e1[4] = {v1.x, v1.y, v1.z, v1.w};
#pragma unroll
      for (int c = 0; c < 4; ++c) {
        int w = j * 4 + c;
        unsigned pk = (unsigned)f2bf(e0[c]) | ((unsigned)f2bf(e1[c]) << 16);
        *(unsigned*)&Ares[w * 512 + (m0 ^ ((w & 7) << 3))] = pk;
      }
    }
  }
  __syncthreads();
  for (int nt = 0; nt < 8; ++nt) {
    int n0 = nt << 6;
    stageB(Bt[0], adjbf, n0, 0, wid, lane);
    __syncthreads();
    f32x4 acc[2][2] = {};
    for (int kt = 0; kt < 8; ++kt) {
      int cur = kt & 1;
      if (kt < 7) stageB(Bt[cur ^ 1], adjbf, n0, kt + 1, wid, lane);
#pragma unroll
      for (int kk = 0; kk < 2; ++kk) {
        int ko = kt * 64 + kk * 32 + (lane >> 4) * 8;
        int eb = kk * 32 + (lane >> 4) * 8;
        int fa0 = wi * 32 + (lane & 15), fa1 = fa0 + 16;
        int nb0 = wj * 32 + (lane & 15), nb1 = nb0 + 16;
        s16x8 a0 = *(const s16x8*)&Ares[fa0 * 512 + (ko ^ ((fa0 & 7) << 3))];
        s16x8 a1 = *(const s16x8*)&Ares[fa1 * 512 + (ko ^ ((fa1 & 7) << 3))];
        s16x8 b0 = *(const s16x8*)&Bt[cur][nb0 * 64 + (eb ^ ((nb0 & 7) << 3))];
        s16x8 b1 = *(const s16x8*)&Bt[cur][nb1 * 64 + (eb ^ ((nb1 & 7) << 3))];
        acc[0][0] = MFMA16(a0, b0, acc[0][0]);
        acc[1][0] = MFMA16(a1, b0, acc[1][0]);
        acc[0][1] = MFMA16(a0, b1, acc[0][1]);
        acc[1][1] = MFMA16(a1, b1, acc[1][1]);
      }
      __syncthreads();
    }
    // D[w][n] -> AX[b][n][w]
    int colb = n0 + wj * 32 + (lane & 15);
    int rowb = wi * 32 + (lane >> 4) * 4;
#pragma unroll
    for (int fi = 0; fi < 2; ++fi)
#pragma unroll
      for (int fj = 0; fj < 2; ++fj) {
        int n = colb + fj * 16, w = rowb + fi * 16;
        ushort4 pk;
        pk.x = f2bf(acc[fi][fj][0]); pk.y = f2bf(acc[fi][fj][1]);
        pk.z = f2bf(acc[fi][fj][2]); pk.w = f2bf(acc[fi][fj][3]);
        *(ushort4*)&AX[((size_t)b * NN + n) * NH + w] = pk;
      }
    __syncthreads();   // before next nt restages Bt[0]
  }
}

// ---------------- H1t = relu(AX @ W1 + b1), + per-node stats ----------------
__global__ __launch_bounds__(256)
void k_h1(const unsigned short* __restrict__ AX, const unsigned short* __restrict__ W1t_i,
          const float* __restrict__ b1_i, unsigned short* __restrict__ H1t,
          float* __restrict__ Ssum, float* __restrict__ Ssq) {
  __shared__ unsigned short At[64 * LDT];
  __shared__ unsigned short Bw[64 * LDT];
  __shared__ float ssum[64], ssq[64];
  int blk = blockIdx.x; int b = blk >> 3; int n0 = (blk & 7) << 6;
  int t = threadIdx.x, lane = t & 63, wid = t >> 6;
  int wi = wid >> 1, wj = wid & 1;
  int r = t >> 2, seg = t & 3;
  if (t < 64) { ssum[t] = 0.f; ssq[t] = 0.f; }
  {
    const unsigned short* aSrc = AX + ((size_t)b * NN + n0 + r) * NH + seg * 16;
    const unsigned short* bSrc = W1t_i + r * 64 + seg * 16;
    *(s16x8*)&At[r * LDT + seg * 16] = *(const s16x8*)aSrc;
    *(s16x8*)&At[r * LDT + seg * 16 + 8] = *(const s16x8*)(aSrc + 8);
    *(s16x8*)&Bw[r * LDT + seg * 16] = *(const s16x8*)bSrc;
    *(s16x8*)&Bw[r * LDT + seg * 16 + 8] = *(const s16x8*)(bSrc + 8);
  }
  __syncthreads();
  f32x4 acc[2][2] = {};
#pragma unroll
  for (int kk = 0; kk < 2; ++kk) {
    int ko = kk * 32 + (lane >> 4) * 8;
    s16x8 a0 = *(const s16x8*)&At[(wi * 32 +  0 + (lane & 15)) * LDT + ko];
    s16x8 a1 = *(const s16x8*)&At[(wi * 32 + 16 + (lane & 15)) * LDT + ko];
    s16x8 b0 = *(const s16x8*)&Bw[(wj * 32 +  0 + (lane & 15)) * LDT + ko];
    s16x8 b1 = *(const s16x8*)&Bw[(wj * 32 + 16 + (lane & 15)) * LDT + ko];
    acc[0][0] = MFMA16(a0, b0, acc[0][0]);
    acc[1][0] = MFMA16(a1, b0, acc[1][0]);
    acc[0][1] = MFMA16(a0, b1, acc[0][1]);
    acc[1][1] = MFMA16(a1, b1, acc[1][1]);
  }
  int fcol = wj * 32 + (lane & 15);
  float bia0 = b1_i[fcol], bia1 = b1_i[fcol + 16];
#pragma unroll
  for (int fi = 0; fi < 2; ++fi) {
    int nloc = wi * 32 + fi * 16 + (lane >> 4) * 4;
    float v0[4], v1[4];
#pragma unroll
    for (int rr = 0; rr < 4; ++rr) {
      float x0 = fmaxf(acc[fi][0][rr] + bia0, 0.f);
      float x1 = fmaxf(acc[fi][1][rr] + bia1, 0.f);
      v0[rr] = x0; v1[rr] = x1;
      float sv = x0 + x1, qv = x0 * x0 + x1 * x1;
      sv += __shfl_xor(sv, 1); sv += __shfl_xor(sv, 2); sv += __shfl_xor(sv, 4); sv += __shfl_xor(sv, 8);
      qv += __shfl_xor(qv, 1); qv += __shfl_xor(qv, 2); qv += __shfl_xor(qv, 4); qv += __shfl_xor(qv, 8);
      if ((lane & 15) == 0) { atomicAdd(&ssum[nloc + rr], sv); atomicAdd(&ssq[nloc + rr], qv); }
    }
    ushort4 p0, p1;
    p0.x = f2bf(v0[0]); p0.y = f2bf(v0[1]); p0.z = f2bf(v0[2]); p0.w = f2bf(v0[3]);
    p1.x = f2bf(v1[0]); p1.y = f2bf(v1[1]); p1.z = f2bf(v1[2]); p1.w = f2bf(v1[3]);
    *(ushort4*)&H1t[((size_t)b * NH + fcol)      * NN + n0 + nloc] = p0;
    *(ushort4*)&H1t[((size_t)b * NH + fcol + 16) * NN + n0 + nloc] = p1;
  }
  __syncthreads();
  if (t < 64) { atomicAdd(&Ssum[n0 + t], ssum[t]); atomicAdd(&Ssq[n0 + t], ssq[t]); }
}

// ---------------- adjB = adj*a1[m]; rc[n] = sum adj[n][m]*c1[m]; BN1 inline ----------------
__global__ __launch_bounds__(256)
void k_adjb(const unsigned short* __restrict__ adjbf,
            const float* __restrict__ Ssum, const float* __restrict__ Ssq,
            const float* __restrict__ g, const float* __restrict__ be,
            unsigned short* __restrict__ adjB, float* __restrict__ rc,
            float* __restrict__ A1, float* __restrict__ C1) {
  __shared__ float red[256];
  int n = blockIdx.x, t = threadIdx.x;
  float acc = 0.f;
#pragma unroll
  for (int hh = 0; hh < 2; ++hh) {
    int m = t + hh * 256;
    float mean = Ssum[m] * (1.f / 65536.f);
    float var  = Ssq[m] * (1.f / 65536.f) - mean * mean;
    float a = g[m] * rsqrtf(var + 1e-5f);
    float c = be[m] - mean * a;
    if (n == 0) { A1[m] = a; C1[m] = c; }
    float av = bf2f(adjbf[n * NN + m]);
    adjB[n * NN + m] = f2bf(av * a);
    acc += av * c;
  }
  red[t] = acc; __syncthreads();
  for (int s = 128; s > 0; s >>= 1) { if (t < s) red[t] += red[t + s]; __syncthreads(); }
  if (t == 0) rc[n] = red[0];
}

// ---------------- skip-min: min over m of a1[m]*H1[m,f]+c1[m] ----------------
__global__ __launch_bounds__(256)
void k_minrow_skip(const unsigned short* __restrict__ Ht, const float* __restrict__ A1,
                   const float* __restrict__ C1, float* __restrict__ skip_i) {
  int t = threadIdx.x, lane = t & 63, wid = t >> 6;
  int row = blockIdx.x * 4 + wid;          // b*64 + f
  s16x8 hv = *(const s16x8*)(Ht + (size_t)row * NN + lane * 8);
  const float* ap = A1 + lane * 8;
  const float* cp = C1 + lane * 8;
  float m = 1e30f;
#pragma unroll
  for (int e = 0; e < 8; ++e) m = fminf(m, ap[e] * bf2f((unsigned short)hv[e]) + cp[e]);
#pragma unroll
  for (int off = 1; off < 64; off <<= 1) m = fminf(m, __shfl_xor(m, off));
  if (lane == 0) skip_i[row] = m;
}

// ---------------- min over n of a2[n]*h2+c2[n] (+skip), BN2 finalize inline ----------------
__global__ __launch_bounds__(256)
void k_minrow_out(const unsigned short* __restrict__ Ht,
                  const float* __restrict__ Ssum, const float* __restrict__ Ssq,
                  const float* __restrict__ g, const float* __restrict__ be,
                  const float* __restrict__ skip_i, float* __restrict__ outs, int i) {
  int t = threadIdx.x, lane = t & 63, wid = t >> 6;
  int row = blockIdx.x * 4 + wid;          // b*64 + d
  int b = row >> 6, d = row & 63;
  s16x8 hv = *(const s16x8*)(Ht + (size_t)row * NN + lane * 8);
  float m = 1e30f;
#pragma unroll
  for (int e = 0; e < 8; ++e) {
    int mm = lane * 8 + e;
    float mean = Ssum[mm] * (1.f / 65536.f);
    float var  = Ssq[mm] * (1.f / 65536.f) - mean * mean;
    float a = g[mm] * rsqrtf(var + 1e-5f);
    float c = be[mm] - mean * a;
    m = fminf(m, a * bf2f((unsigned short)hv[e]) + c);
  }
#pragma unroll
  for (int off = 1; off < 64; off <<= 1) m = fminf(m, __shfl_xor(m, off));
  if (lane == 0) outs[(size_t)b * 192 + i * 64 + d] = m + skip_i[row];
}

// ---------------- layer2: block per b, H1t[b] resident; 2-stage GEMM ----------------
__global__ __launch_bounds__(256)
void k_layer2(const unsigned short* __restrict__ H1t, const unsigned short* __restrict__ adjB,
              const float* __restrict__ rc, const unsigned short* __restrict__ W2t_i,
              const float* __restrict__ b2_i, unsigned short* __restrict__ H2t,
              float* __restrict__ Ssum, float* __restrict__ Ssq) {
  __shared__ unsigned short Ares[64 * 512];     // H1t[b]: [f][m swz]
  __shared__ unsigned short Bt[2][64 * 64];     // adjB tiles; Bt[0] reused as Gt
  int b = blockIdx.x, t = threadIdx.x, lane = t & 63, wid = t >> 6;
  int wi = wid >> 1, wj = wid & 1;
  // stage Ares (wave wid: rows wid*16..+15), 1KB rows via global_load_lds
  {
    const unsigned short* base = H1t + (size_t)b * (NH * NN);
#pragma unroll
    for (int it = 0; it < 16; ++it) {
      int f = wid * 16 + it;
      const unsigned short* gsrc = base + f * NN + ((lane ^ (f & 7)) << 3);
      GLOAD16(gsrc, &Ares[f * 512]);
    }
  }
  // W2 fragments in registers (rows d, k=f)
  s16x8 w2f[2][2];
#pragma unroll
  for (int kk = 0; kk < 2; ++kk) {
    int e = kk * 32 + (lane >> 4) * 8;
    w2f[kk][0] = *(const s16x8*)&W2t_i[(wj * 32      + (lane & 15)) * 64 + e];
    w2f[kk][1] = *(const s16x8*)&W2t_i[(wj * 32 + 16 + (lane & 15)) * 64 + e];
  }
  float bb0 = b2_i[wj * 32 + (lane & 15)], bb1 = b2_i[wj * 32 + 16 + (lane & 15)];
  __syncthreads();   // Ares ready

  for (int nt = 0; nt < 8; ++nt) {
    int n0 = nt << 6;
    int ncol = wj * 32 + (lane & 15);
    float rc0 = rc[n0 + ncol], rc1 = rc[n0 + ncol + 16];
    stageB(Bt[0], adjB, n0, 0, wid, lane);
    __syncthreads();
    f32x4 acc[2][2] = {};
    for (int kt = 0; kt < 8; ++kt) {
      int cur = kt & 1;
      if (kt < 7) stageB(Bt[cur ^ 1], adjB, n0, kt + 1, wid, lane);
#pragma unroll
      for (int kk = 0; kk < 2; ++kk) {
        int ko = kt * 64 + kk * 32 + (lane >> 4) * 8;
        int eb = kk * 32 + (lane >> 4) * 8;
        int fa0 = wi * 32 + (lane & 15), fa1 = fa0 + 16;
        int nb0 = wj * 32 + (lane & 15), nb1 = nb0 + 16;
        s16x8 a0 = *(const s16x8*)&Ares[fa0 * 512 + (ko ^ ((fa0 & 7) << 3))];
        s16x8 a1 = *(const s16x8*)&Ares[fa1 * 512 + (ko ^ ((fa1 & 7) << 3))];
        s16x8 b0 = *(const s16x8*)&Bt[cur][nb0 * 64 + (eb ^ ((nb0 & 7) << 3))];
        s16x8 b1 = *(const s16x8*)&Bt[cur][nb1 * 64 + (eb ^ ((nb1 & 7) << 3))];
        acc[0][0] = MFMA16(a0, b0, acc[0][0]);
        acc[1][0] = MFMA16(a1, b0, acc[1][0]);
        acc[0][1] = MFMA16(a0, b1, acc[0][1]);
        acc[1][1] = MFMA16(a1, b1, acc[1][1]);
      }
      __syncthreads();
    }
    // G[n][f] = D1[f][n] + rc[n]  -> Bt[0] (swizzled), bf16
    unsigned short* Gt = Bt[0];
#pragma unroll
    for (int fi = 0; fi < 2; ++fi) {
      int floc = wi * 32 + fi * 16 + (lane >> 4) * 4;
      ushort4 p0, p1;
      p0.x = f2bf(acc[fi][0][0] + rc0); p0.y = f2bf(acc[fi][0][1] + rc0);
      p0.z = f2bf(acc[fi][0][2] + rc0); p0.w = f2bf(acc[fi][0][3] + rc0);
      p1.x = f2bf(acc[fi][1][0] + rc1); p1.y = f2bf(acc[fi][1][1] + rc1);
      p1.z = f2bf(acc[fi][1][2] + rc1); p1.w = f2bf(acc[fi][1][3] + rc1);
      int gn0 = ncol, gn1 = ncol + 16;
      *(ushort4*)&Gt[gn0 * 64 + (floc ^ ((gn0 & 7) << 3))] = p0;
      *(ushort4*)&Gt[gn1 * 64 + (floc ^ ((gn1 & 7) << 3))] = p1;
    }
    __syncthreads();
    // stage2: D2[n][d] = sum_f G[n][f] * W2t[d][f]
    f32x4 acc2[2][2] = {};
#pragma unroll
    for (int kk = 0; kk < 2; ++kk) {
      int e = kk * 32 + (lane >> 4) * 8;
      int na0 = wi * 32 + (lane & 15), na1 = na0 + 16;
      s16x8 a0 = *(const s16x8*)&Gt[na0 * 64 + (e ^ ((na0 & 7) << 3))];
      s16x8 a1 = *(const s16x8*)&Gt[na1 * 64 + (e ^ ((na1 & 7) << 3))];
      acc2[0][0] = MFMA16(a0, w2f[kk][0], acc2[0][0]);
      acc2[1][0] = MFMA16(a1, w2f[kk][0], acc2[1][0]);
      acc2[0][1] = MFMA16(a0, w2f[kk][1], acc2[0][1]);
      acc2[1][1] = MFMA16(a1, w2f[kk][1], acc2[1][1]);
    }
    int dcol = wj * 32 + (lane & 15);
#pragma unroll
    for (int fi = 0; fi < 2; ++fi) {
      int nloc = wi * 32 + fi * 16 + (lane >> 4) * 4;
      float v0[4], v1[4];
#pragma unroll
      for (int rr = 0; rr < 4; ++rr) {
        float x0 = fmaxf(acc2[fi][0][rr] + bb0, 0.f);
        float x1 = fmaxf(acc2[fi][1][rr] + bb1, 0.f);
        v0[rr] = x0; v1[rr] = x1;
        float sv = x0 + x1, qv = x0 * x0 + x1 * x1;
        sv += __shfl_xor(sv, 1); sv += __shfl_xor(sv, 2); sv += __shfl_xor(sv, 4); sv += __shfl_xor(sv, 8);
        qv += __shfl_xor(qv, 1); qv += __shfl_xor(qv, 2); qv += __shfl_xor(qv, 4); qv += __shfl_xor(qv, 8);
        if ((lane & 15) == 0) {
          atomicAdd(&Ssum[n0 + nloc + rr], sv);
          atomicAdd(&Ssq[n0 + nloc + rr], qv);
        }
      }
      ushort4 p0, p1;
      p0.x = f2bf(v0[0]); p0.y = f2bf(v0[1]); p0.z = f2bf(v0[2]); p0.w = f2bf(v0[3]);
      p1.x = f2bf(v1[0]); p1.y = f2bf(v1[1]); p1.z = f2bf(v1[2]); p1.w = f2bf(v1[3]);
      *(ushort4*)&H2t[((size_t)b * NH + dcol)      * NN + n0 + nloc] = p0;
      *(ushort4*)&H2t[((size_t)b * NH + dcol + 16) * NN + n0 + nloc] = p1;
    }
    __syncthreads();   // all Gt reads done before next nt restages Bt[0]
  }
}

// ---------------- final FC ----------------
__global__ __launch_bounds__(256)
void k_fc(const float* __restrict__ outs, const float* __restrict__ Wfc,
          const float* __restrict__ bfc, float* __restrict__ out) {
  int t = threadIdx.x;
  int b = blockIdx.x * 8 + (t >> 5), o = t & 31;
  float acc = bfc[o];
  const float* orow = outs + (size_t)b * 192;
  for (int j = 0; j < 192; ++j) acc += orow[j] * Wfc[j * 32 + o];
  out[b * 32 + o] = acc;
}

extern "C" void kernel_launch(void* const* d_in, const int* in_sizes, int n_in,
                              void* d_out, int out_size, void* d_ws, size_t ws_size,
                              hipStream_t stream) {
  const float* X   = (const float*)d_in[0];
  const float* adj = (const float*)d_in[1];
  const float* W1  = (const float*)d_in[2];
  const float* b1  = (const float*)d_in[3];
  const float* g1  = (const float*)d_in[4];
  const float* be1 = (const float*)d_in[5];
  const float* W2  = (const float*)d_in[6];
  const float* b2  = (const float*)d_in[7];
  const float* g2  = (const float*)d_in[8];
  const float* be2 = (const float*)d_in[9];
  const float* Wfc = (const float*)d_in[10];
  const float* bfc = (const float*)d_in[11];
  float* out = (float*)d_out;

  char* ws = (char*)d_ws;
  size_t off = 0;
  auto alloc = [&](size_t bytes) {
    char* p = ws + off; off += (bytes + 255) & ~(size_t)255; return p;
  };
  unsigned short* ADJBF = (unsigned short*)alloc(512 * 512 * 2);
  unsigned short* ADJB  = (unsigned short*)alloc(512 * 512 * 2);
  unsigned short* W1T   = (unsigned short*)alloc(3 * 4096 * 2);
  unsigned short* W2T   = (unsigned short*)alloc(3 * 4096 * 2);
  float* SS1 = (float*)alloc(3 * 512 * 4);   // contiguous 4x6144B for one memset
  float* SQ1 = (float*)alloc(3 * 512 * 4);
  float* SS2 = (float*)alloc(3 * 512 * 4);
  float* SQ2 = (float*)alloc(3 * 512 * 4);
  float* A1  = (float*)alloc(3 * 512 * 4);
  float* C1  = (float*)alloc(3 * 512 * 4);
  float* RC  = (float*)alloc(512 * 4);
  float* SKIP = (float*)alloc(3 * 1024 * 64 * 4);
  float* OUTS = (float*)alloc(1024 * 192 * 4);
  unsigned short* AX  = (unsigned short*)alloc((size_t)1024 * 512 * 64 * 2);
  unsigned short* H1T = (unsigned short*)alloc((size_t)1024 * 64 * 512 * 2);
  unsigned short* H2T = (unsigned short*)alloc((size_t)1024 * 64 * 512 * 2);

  hipMemsetAsync(SS1, 0, 4 * 3 * 512 * 4, stream);

  k_prep_adj<<<1024, 256, 0, stream>>>(adj, ADJBF);
  k_prep_w<<<48, 256, 0, stream>>>(W1, W2, W1T, W2T);
  k_gemm_ax<<<1024, 256, 0, stream>>>(X, ADJBF, AX);

  for (int i = 0; i < 3; ++i) {
    k_h1<<<8192, 256, 0, stream>>>(AX, W1T + i * 4096, b1 + i * 64, H1T,
                                   SS1 + i * 512, SQ1 + i * 512);
    k_adjb<<<512, 256, 0, stream>>>(ADJBF, SS1 + i * 512, SQ1 + i * 512,
                                    g1 + i * 512, be1 + i * 512, ADJB, RC,
                                    A1 + i * 512, C1 + i * 512);
    k_minrow_skip<<<16384, 256, 0, stream>>>(H1T, A1 + i * 512, C1 + i * 512,
                                             SKIP + i * 65536);
    k_layer2<<<1024, 256, 0, stream>>>(H1T, ADJB, RC, W2T + i * 4096, b2 + i * 64, H2T,
                                       SS2 + i * 512, SQ2 + i * 512);
    k_minrow_out<<<16384, 256, 0, stream>>>(H2T, SS2 + i * 512, SQ2 + i * 512,
                                            g2 + i * 512, be2 + i * 512,
                                            SKIP + i * 65536, OUTS, i);
  }
  k_fc<<<128, 256, 0, stream>>>(OUTS, Wfc, bfc, out);
}

// Round 4
// 760.332 us; speedup vs baseline: 3.1334x; 3.1334x over previous
//
#include <hip/hip_runtime.h>

// GNNTEP R4: R3 structure, but BN2 stats moved OUT of k_layer2's nt-loop
// (global atomics + barrier inside the loop serialized all 1024 blocks on
// 128 contended addresses -> 780us pure stall). k_layer2 is now pure
// GEMM->relu->store; new k_stats2 does the per-node reduction separately
// with fire-and-forget atomics at kernel end (the k_h1 pattern).

typedef short  s16x8 __attribute__((ext_vector_type(8)));
typedef float  f32x4 __attribute__((ext_vector_type(4)));

#define NN   512
#define NB   1024
#define NH   64
#define LDT  72   // k_h1 LDS row stride

#define MFMA16(a, b, c) __builtin_amdgcn_mfma_f32_16x16x32_bf16((a), (b), (c), 0, 0, 0)

#define GLOAD16(g, l) __builtin_amdgcn_global_load_lds( \
    (const __attribute__((address_space(1))) unsigned*)(g), \
    (__attribute__((address_space(3))) unsigned*)(l), 16, 0, 0)

__device__ __forceinline__ unsigned short f2bf(float f) {
  union { float f; unsigned u; } v; v.f = f;
  unsigned r = v.u + 0x7fffu + ((v.u >> 16) & 1u);   // RNE
  return (unsigned short)(r >> 16);
}
__device__ __forceinline__ float bf2f(unsigned short h) {
  union { unsigned u; float f; } v; v.u = ((unsigned)h) << 16;
  return v.f;
}

// Stage one 64x64 bf16 B-tile (rows n0..n0+63, k-slice kt) into LDS with
// in-row 16B-slot XOR swizzle: LDS[n][slot] = G[n][slot ^ (n&7)].
__device__ __forceinline__ void stageB(unsigned short* buf, const unsigned short* __restrict__ src,
                                       int n0, int kt, int wid, int lane) {
#pragma unroll
  for (int q = 0; q < 2; ++q) {
    int g = wid * 2 + q;                    // 8-row group
    const unsigned short* gsrc = src + (size_t)(n0 + g * 8 + (lane >> 3)) * NN
                                     + kt * 64 + (((lane & 7) ^ (lane >> 3)) << 3);
    GLOAD16(gsrc, &buf[g * 512]);
  }
}

// ---------------- prep ----------------
__global__ void k_prep_adj(const float* __restrict__ adj, unsigned short* __restrict__ adjbf) {
  int idx = blockIdx.x * 256 + threadIdx.x;        // 512*512
  int n = idx >> 9, m = idx & 511;
  float v = adj[idx];
  if (n == m) v = 0.f;
  adjbf[idx] = f2bf(v);
}

// W1t[i][f][w] = W1[i][w][f];  W2t[i][d][f] = W2[i][f][d]
__global__ void k_prep_w(const float* __restrict__ W1, const float* __restrict__ W2,
                         unsigned short* __restrict__ W1t, unsigned short* __restrict__ W2t) {
  int idx = blockIdx.x * 256 + threadIdx.x;        // 3*64*64
  int i = idx >> 12, rc_ = idx & 4095;
  int src = (i << 12) + ((rc_ & 63) << 6) + (rc_ >> 6);
  W1t[idx] = f2bf(W1[src]);
  W2t[idx] = f2bf(W2[src]);
}

// ---------------- AX = adj @ X, block per b, A=X^T resident ----------------
__global__ __launch_bounds__(256)
void k_gemm_ax(const float* __restrict__ X, const unsigned short* __restrict__ adjbf,
               unsigned short* __restrict__ AX) {
  __shared__ unsigned short Ares[64 * 512];     // [w][m swz]
  __shared__ unsigned short Bt[2][64 * 64];
  int b = blockIdx.x, t = threadIdx.x, lane = t & 63, wid = t >> 6;
  int wi = wid >> 1, wj = wid & 1;
  // transpose-stage X[b] (f32 [512 m][64 w]) -> Ares[w][m] bf16, swizzled
  {
    const float* xb = X + (size_t)b * (NN * NH);
    int m0 = t * 2;
    const float4* r0 = (const float4*)(xb + (size_t)m0 * NH);
    const float4* r1 = (const float4*)(xb + (size_t)(m0 + 1) * NH);
#pragma unroll
    for (int j = 0; j < 16; ++j) {
      float4 v0 = r0[j], v1 = r1[j];
      float e0[4] = {v0.x, v0.y, v0.z, v0.w};
      float e1[4] = {v1.x, v1.y, v1.z, v1.w};
#pragma unroll
      for (int c = 0; c < 4; ++c) {
        int w = j * 4 + c;
        unsigned pk = (unsigned)f2bf(e0[c]) | ((unsigned)f2bf(e1[c]) << 16);
        *(unsigned*)&Ares[w * 512 + (m0 ^ ((w & 7) << 3))] = pk;
      }
    }
  }
  __syncthreads();
  for (int nt = 0; nt < 8; ++nt) {
    int n0 = nt << 6;
    stageB(Bt[0], adjbf, n0, 0, wid, lane);
    __syncthreads();
    f32x4 acc[2][2] = {};
    for (int kt = 0; kt < 8; ++kt) {
      int cur = kt & 1;
      if (kt < 7) stageB(Bt[cur ^ 1], adjbf, n0, kt + 1, wid, lane);
#pragma unroll
      for (int kk = 0; kk < 2; ++kk) {
        int ko = kt * 64 + kk * 32 + (lane >> 4) * 8;
        int eb = kk * 32 + (lane >> 4) * 8;
        int fa0 = wi * 32 + (lane & 15), fa1 = fa0 + 16;
        int nb0 = wj * 32 + (lane & 15), nb1 = nb0 + 16;
        s16x8 a0 = *(const s16x8*)&Ares[fa0 * 512 + (ko ^ ((fa0 & 7) << 3))];
        s16x8 a1 = *(const s16x8*)&Ares[fa1 * 512 + (ko ^ ((fa1 & 7) << 3))];
        s16x8 b0 = *(const s16x8*)&Bt[cur][nb0 * 64 + (eb ^ ((nb0 & 7) << 3))];
        s16x8 b1 = *(const s16x8*)&Bt[cur][nb1 * 64 + (eb ^ ((nb1 & 7) << 3))];
        acc[0][0] = MFMA16(a0, b0, acc[0][0]);
        acc[1][0] = MFMA16(a1, b0, acc[1][0]);
        acc[0][1] = MFMA16(a0, b1, acc[0][1]);
        acc[1][1] = MFMA16(a1, b1, acc[1][1]);
      }
      __syncthreads();
    }
    // D[w][n] -> AX[b][n][w]
    int colb = n0 + wj * 32 + (lane & 15);
    int rowb = wi * 32 + (lane >> 4) * 4;
#pragma unroll
    for (int fi = 0; fi < 2; ++fi)
#pragma unroll
      for (int fj = 0; fj < 2; ++fj) {
        int n = colb + fj * 16, w = rowb + fi * 16;
        ushort4 pk;
        pk.x = f2bf(acc[fi][fj][0]); pk.y = f2bf(acc[fi][fj][1]);
        pk.z = f2bf(acc[fi][fj][2]); pk.w = f2bf(acc[fi][fj][3]);
        *(ushort4*)&AX[((size_t)b * NN + n) * NH + w] = pk;
      }
    __syncthreads();   // before next nt restages Bt[0]
  }
}

// ---------------- H1t = relu(AX @ W1 + b1), + per-node stats ----------------
__global__ __launch_bounds__(256)
void k_h1(const unsigned short* __restrict__ AX, const unsigned short* __restrict__ W1t_i,
          const float* __restrict__ b1_i, unsigned short* __restrict__ H1t,
          float* __restrict__ Ssum, float* __restrict__ Ssq) {
  __shared__ unsigned short At[64 * LDT];
  __shared__ unsigned short Bw[64 * LDT];
  __shared__ float ssum[64], ssq[64];
  int blk = blockIdx.x; int b = blk >> 3; int n0 = (blk & 7) << 6;
  int t = threadIdx.x, lane = t & 63, wid = t >> 6;
  int wi = wid >> 1, wj = wid & 1;
  int r = t >> 2, seg = t & 3;
  if (t < 64) { ssum[t] = 0.f; ssq[t] = 0.f; }
  {
    const unsigned short* aSrc = AX + ((size_t)b * NN + n0 + r) * NH + seg * 16;
    const unsigned short* bSrc = W1t_i + r * 64 + seg * 16;
    *(s16x8*)&At[r * LDT + seg * 16] = *(const s16x8*)aSrc;
    *(s16x8*)&At[r * LDT + seg * 16 + 8] = *(const s16x8*)(aSrc + 8);
    *(s16x8*)&Bw[r * LDT + seg * 16] = *(const s16x8*)bSrc;
    *(s16x8*)&Bw[r * LDT + seg * 16 + 8] = *(const s16x8*)(bSrc + 8);
  }
  __syncthreads();
  f32x4 acc[2][2] = {};
#pragma unroll
  for (int kk = 0; kk < 2; ++kk) {
    int ko = kk * 32 + (lane >> 4) * 8;
    s16x8 a0 = *(const s16x8*)&At[(wi * 32 +  0 + (lane & 15)) * LDT + ko];
    s16x8 a1 = *(const s16x8*)&At[(wi * 32 + 16 + (lane & 15)) * LDT + ko];
    s16x8 b0 = *(const s16x8*)&Bw[(wj * 32 +  0 + (lane & 15)) * LDT + ko];
    s16x8 b1 = *(const s16x8*)&Bw[(wj * 32 + 16 + (lane & 15)) * LDT + ko];
    acc[0][0] = MFMA16(a0, b0, acc[0][0]);
    acc[1][0] = MFMA16(a1, b0, acc[1][0]);
    acc[0][1] = MFMA16(a0, b1, acc[0][1]);
    acc[1][1] = MFMA16(a1, b1, acc[1][1]);
  }
  int fcol = wj * 32 + (lane & 15);
  float bia0 = b1_i[fcol], bia1 = b1_i[fcol + 16];
#pragma unroll
  for (int fi = 0; fi < 2; ++fi) {
    int nloc = wi * 32 + fi * 16 + (lane >> 4) * 4;
    float v0[4], v1[4];
#pragma unroll
    for (int rr = 0; rr < 4; ++rr) {
      float x0 = fmaxf(acc[fi][0][rr] + bia0, 0.f);
      float x1 = fmaxf(acc[fi][1][rr] + bia1, 0.f);
      v0[rr] = x0; v1[rr] = x1;
      float sv = x0 + x1, qv = x0 * x0 + x1 * x1;
      sv += __shfl_xor(sv, 1); sv += __shfl_xor(sv, 2); sv += __shfl_xor(sv, 4); sv += __shfl_xor(sv, 8);
      qv += __shfl_xor(qv, 1); qv += __shfl_xor(qv, 2); qv += __shfl_xor(qv, 4); qv += __shfl_xor(qv, 8);
      if ((lane & 15) == 0) { atomicAdd(&ssum[nloc + rr], sv); atomicAdd(&ssq[nloc + rr], qv); }
    }
    ushort4 p0, p1;
    p0.x = f2bf(v0[0]); p0.y = f2bf(v0[1]); p0.z = f2bf(v0[2]); p0.w = f2bf(v0[3]);
    p1.x = f2bf(v1[0]); p1.y = f2bf(v1[1]); p1.z = f2bf(v1[2]); p1.w = f2bf(v1[3]);
    *(ushort4*)&H1t[((size_t)b * NH + fcol)      * NN + n0 + nloc] = p0;
    *(ushort4*)&H1t[((size_t)b * NH + fcol + 16) * NN + n0 + nloc] = p1;
  }
  __syncthreads();
  if (t < 64) { atomicAdd(&Ssum[n0 + t], ssum[t]); atomicAdd(&Ssq[n0 + t], ssq[t]); }
}

// ---------------- adjB = adj*a1[m]; rc[n] = sum adj[n][m]*c1[m]; BN1 inline ----------------
__global__ __launch_bounds__(256)
void k_adjb(const unsigned short* __restrict__ adjbf,
            const float* __restrict__ Ssum, const float* __restrict__ Ssq,
            const float* __restrict__ g, const float* __restrict__ be,
            unsigned short* __restrict__ adjB, float* __restrict__ rc,
            float* __restrict__ A1, float* __restrict__ C1) {
  __shared__ float red[256];
  int n = blockIdx.x, t = threadIdx.x;
  float acc = 0.f;
#pragma unroll
  for (int hh = 0; hh < 2; ++hh) {
    int m = t + hh * 256;
    float mean = Ssum[m] * (1.f / 65536.f);
    float var  = Ssq[m] * (1.f / 65536.f) - mean * mean;
    float a = g[m] * rsqrtf(var + 1e-5f);
    float c = be[m] - mean * a;
    if (n == 0) { A1[m] = a; C1[m] = c; }
    float av = bf2f(adjbf[n * NN + m]);
    adjB[n * NN + m] = f2bf(av * a);
    acc += av * c;
  }
  red[t] = acc; __syncthreads();
  for (int s = 128; s > 0; s >>= 1) { if (t < s) red[t] += red[t + s]; __syncthreads(); }
  if (t == 0) rc[n] = red[0];
}

// ---------------- skip-min: min over m of a1[m]*H1[m,f]+c1[m] ----------------
__global__ __launch_bounds__(256)
void k_minrow_skip(const unsigned short* __restrict__ Ht, const float* __restrict__ A1,
                   const float* __restrict__ C1, float* __restrict__ skip_i) {
  int t = threadIdx.x, lane = t & 63, wid = t >> 6;
  int row = blockIdx.x * 4 + wid;          // b*64 + f
  s16x8 hv = *(const s16x8*)(Ht + (size_t)row * NN + lane * 8);
  const float* ap = A1 + lane * 8;
  const float* cp = C1 + lane * 8;
  float m = 1e30f;
#pragma unroll
  for (int e = 0; e < 8; ++e) m = fminf(m, ap[e] * bf2f((unsigned short)hv[e]) + cp[e]);
#pragma unroll
  for (int off = 1; off < 64; off <<= 1) m = fminf(m, __shfl_xor(m, off));
  if (lane == 0) skip_i[row] = m;
}

// ---------------- BN2 stats over H2t: per-node sum/sumsq (block per b) ----------------
__global__ __launch_bounds__(256)
void k_stats2(const unsigned short* __restrict__ H2t,
              float* __restrict__ Ssum, float* __restrict__ Ssq) {
  __shared__ float ls[512], lq[512];
  int b = blockIdx.x, t = threadIdx.x, lane = t & 63, wid = t >> 6;
  ls[t] = 0.f; ls[t + 256] = 0.f; lq[t] = 0.f; lq[t + 256] = 0.f;
  float s[8] = {}, q[8] = {};
  const unsigned short* base = H2t + (size_t)b * (NH * NN);
  for (int it = 0; it < 16; ++it) {
    int d = wid * 16 + it;
    s16x8 hv = *(const s16x8*)(base + (size_t)d * NN + lane * 8);
#pragma unroll
    for (int e = 0; e < 8; ++e) { float x = bf2f((unsigned short)hv[e]); s[e] += x; q[e] += x * x; }
  }
  __syncthreads();
#pragma unroll
  for (int e = 0; e < 8; ++e) {
    atomicAdd(&ls[lane * 8 + e], s[e]);
    atomicAdd(&lq[lane * 8 + e], q[e]);
  }
  __syncthreads();
  // fire-and-forget global flush (no trailing barrier)
  atomicAdd(&Ssum[t], ls[t]);       atomicAdd(&Ssum[t + 256], ls[t + 256]);
  atomicAdd(&Ssq[t],  lq[t]);       atomicAdd(&Ssq[t + 256],  lq[t + 256]);
}

// ---------------- min over n of a2[n]*h2+c2[n] (+skip), BN2 finalize inline ----------------
__global__ __launch_bounds__(256)
void k_minrow_out(const unsigned short* __restrict__ Ht,
                  const float* __restrict__ Ssum, const float* __restrict__ Ssq,
                  const float* __restrict__ g, const float* __restrict__ be,
                  const float* __restrict__ skip_i, float* __restrict__ outs, int i) {
  int t = threadIdx.x, lane = t & 63, wid = t >> 6;
  int row = blockIdx.x * 4 + wid;          // b*64 + d
  int b = row >> 6, d = row & 63;
  s16x8 hv = *(const s16x8*)(Ht + (size_t)row * NN + lane * 8);
  float m = 1e30f;
#pragma unroll
  for (int e = 0; e < 8; ++e) {
    int mm = lane * 8 + e;
    float mean = Ssum[mm] * (1.f / 65536.f);
    float var  = Ssq[mm] * (1.f / 65536.f) - mean * mean;
    float a = g[mm] * rsqrtf(var + 1e-5f);
    float c = be[mm] - mean * a;
    m = fminf(m, a * bf2f((unsigned short)hv[e]) + c);
  }
#pragma unroll
  for (int off = 1; off < 64; off <<= 1) m = fminf(m, __shfl_xor(m, off));
  if (lane == 0) outs[(size_t)b * 192 + i * 64 + d] = m + skip_i[row];
}

// ---------------- layer2: block per b, H1t[b] resident; 2-stage GEMM, no stats ----------------
__global__ __launch_bounds__(256)
void k_layer2(const unsigned short* __restrict__ H1t, const unsigned short* __restrict__ adjB,
              const float* __restrict__ rc, const unsigned short* __restrict__ W2t_i,
              const float* __restrict__ b2_i, unsigned short* __restrict__ H2t) {
  __shared__ unsigned short Ares[64 * 512];     // H1t[b]: [f][m swz]
  __shared__ unsigned short Bt[2][64 * 64];     // adjB tiles; Bt[0] reused as Gt
  int b = blockIdx.x, t = threadIdx.x, lane = t & 63, wid = t >> 6;
  int wi = wid >> 1, wj = wid & 1;
  // stage Ares (wave wid: rows wid*16..+15), 1KB rows via global_load_lds
  {
    const unsigned short* base = H1t + (size_t)b * (NH * NN);
#pragma unroll
    for (int it = 0; it < 16; ++it) {
      int f = wid * 16 + it;
      const unsigned short* gsrc = base + f * NN + ((lane ^ (f & 7)) << 3);
      GLOAD16(gsrc, &Ares[f * 512]);
    }
  }
  // W2 fragments in registers (rows d, k=f)
  s16x8 w2f[2][2];
#pragma unroll
  for (int kk = 0; kk < 2; ++kk) {
    int e = kk * 32 + (lane >> 4) * 8;
    w2f[kk][0] = *(const s16x8*)&W2t_i[(wj * 32      + (lane & 15)) * 64 + e];
    w2f[kk][1] = *(const s16x8*)&W2t_i[(wj * 32 + 16 + (lane & 15)) * 64 + e];
  }
  float bb0 = b2_i[wj * 32 + (lane & 15)], bb1 = b2_i[wj * 32 + 16 + (lane & 15)];
  __syncthreads();   // Ares ready

  for (int nt = 0; nt < 8; ++nt) {
    int n0 = nt << 6;
    int ncol = wj * 32 + (lane & 15);
    float rc0 = rc[n0 + ncol], rc1 = rc[n0 + ncol + 16];
    stageB(Bt[0], adjB, n0, 0, wid, lane);
    __syncthreads();
    f32x4 acc[2][2] = {};
    for (int kt = 0; kt < 8; ++kt) {
      int cur = kt & 1;
      if (kt < 7) stageB(Bt[cur ^ 1], adjB, n0, kt + 1, wid, lane);
#pragma unroll
      for (int kk = 0; kk < 2; ++kk) {
        int ko = kt * 64 + kk * 32 + (lane >> 4) * 8;
        int eb = kk * 32 + (lane >> 4) * 8;
        int fa0 = wi * 32 + (lane & 15), fa1 = fa0 + 16;
        int nb0 = wj * 32 + (lane & 15), nb1 = nb0 + 16;
        s16x8 a0 = *(const s16x8*)&Ares[fa0 * 512 + (ko ^ ((fa0 & 7) << 3))];
        s16x8 a1 = *(const s16x8*)&Ares[fa1 * 512 + (ko ^ ((fa1 & 7) << 3))];
        s16x8 b0 = *(const s16x8*)&Bt[cur][nb0 * 64 + (eb ^ ((nb0 & 7) << 3))];
        s16x8 b1 = *(const s16x8*)&Bt[cur][nb1 * 64 + (eb ^ ((nb1 & 7) << 3))];
        acc[0][0] = MFMA16(a0, b0, acc[0][0]);
        acc[1][0] = MFMA16(a1, b0, acc[1][0]);
        acc[0][1] = MFMA16(a0, b1, acc[0][1]);
        acc[1][1] = MFMA16(a1, b1, acc[1][1]);
      }
      __syncthreads();
    }
    // G[n][f] = D1[f][n] + rc[n]  -> Bt[0] (swizzled), bf16
    unsigned short* Gt = Bt[0];
#pragma unroll
    for (int fi = 0; fi < 2; ++fi) {
      int floc = wi * 32 + fi * 16 + (lane >> 4) * 4;
      ushort4 p0, p1;
      p0.x = f2bf(acc[fi][0][0] + rc0); p0.y = f2bf(acc[fi][0][1] + rc0);
      p0.z = f2bf(acc[fi][0][2] + rc0); p0.w = f2bf(acc[fi][0][3] + rc0);
      p1.x = f2bf(acc[fi][1][0] + rc1); p1.y = f2bf(acc[fi][1][1] + rc1);
      p1.z = f2bf(acc[fi][1][2] + rc1); p1.w = f2bf(acc[fi][1][3] + rc1);
      int gn0 = ncol, gn1 = ncol + 16;
      *(ushort4*)&Gt[gn0 * 64 + (floc ^ ((gn0 & 7) << 3))] = p0;
      *(ushort4*)&Gt[gn1 * 64 + (floc ^ ((gn1 & 7) << 3))] = p1;
    }
    __syncthreads();
    // stage2: D2[n][d] = sum_f G[n][f] * W2t[d][f]
    f32x4 acc2[2][2] = {};
#pragma unroll
    for (int kk = 0; kk < 2; ++kk) {
      int e = kk * 32 + (lane >> 4) * 8;
      int na0 = wi * 32 + (lane & 15), na1 = na0 + 16;
      s16x8 a0 = *(const s16x8*)&Gt[na0 * 64 + (e ^ ((na0 & 7) << 3))];
      s16x8 a1 = *(const s16x8*)&Gt[na1 * 64 + (e ^ ((na1 & 7) << 3))];
      acc2[0][0] = MFMA16(a0, w2f[kk][0], acc2[0][0]);
      acc2[1][0] = MFMA16(a1, w2f[kk][0], acc2[1][0]);
      acc2[0][1] = MFMA16(a0, w2f[kk][1], acc2[0][1]);
      acc2[1][1] = MFMA16(a1, w2f[kk][1], acc2[1][1]);
    }
    int dcol = wj * 32 + (lane & 15);
#pragma unroll
    for (int fi = 0; fi < 2; ++fi) {
      int nloc = wi * 32 + fi * 16 + (lane >> 4) * 4;
      ushort4 p0, p1;
      p0.x = f2bf(fmaxf(acc2[fi][0][0] + bb0, 0.f));
      p0.y = f2bf(fmaxf(acc2[fi][0][1] + bb0, 0.f));
      p0.z = f2bf(fmaxf(acc2[fi][0][2] + bb0, 0.f));
      p0.w = f2bf(fmaxf(acc2[fi][0][3] + bb0, 0.f));
      p1.x = f2bf(fmaxf(acc2[fi][1][0] + bb1, 0.f));
      p1.y = f2bf(fmaxf(acc2[fi][1][1] + bb1, 0.f));
      p1.z = f2bf(fmaxf(acc2[fi][1][2] + bb1, 0.f));
      p1.w = f2bf(fmaxf(acc2[fi][1][3] + bb1, 0.f));
      *(ushort4*)&H2t[((size_t)b * NH + dcol)      * NN + n0 + nloc] = p0;
      *(ushort4*)&H2t[((size_t)b * NH + dcol + 16) * NN + n0 + nloc] = p1;
    }
    __syncthreads();   // all Gt reads done before next nt restages Bt[0]
  }
}

// ---------------- final FC ----------------
__global__ __launch_bounds__(256)
void k_fc(const float* __restrict__ outs, const float* __restrict__ Wfc,
          const float* __restrict__ bfc, float* __restrict__ out) {
  int t = threadIdx.x;
  int b = blockIdx.x * 8 + (t >> 5), o = t & 31;
  float acc = bfc[o];
  const float* orow = outs + (size_t)b * 192;
  for (int j = 0; j < 192; ++j) acc += orow[j] * Wfc[j * 32 + o];
  out[b * 32 + o] = acc;
}

extern "C" void kernel_launch(void* const* d_in, const int* in_sizes, int n_in,
                              void* d_out, int out_size, void* d_ws, size_t ws_size,
                              hipStream_t stream) {
  const float* X   = (const float*)d_in[0];
  const float* adj = (const float*)d_in[1];
  const float* W1  = (const float*)d_in[2];
  const float* b1  = (const float*)d_in[3];
  const float* g1  = (const float*)d_in[4];
  const float* be1 = (const float*)d_in[5];
  const float* W2  = (const float*)d_in[6];
  const float* b2  = (const float*)d_in[7];
  const float* g2  = (const float*)d_in[8];
  const float* be2 = (const float*)d_in[9];
  const float* Wfc = (const float*)d_in[10];
  const float* bfc = (const float*)d_in[11];
  float* out = (float*)d_out;

  char* ws = (char*)d_ws;
  size_t off = 0;
  auto alloc = [&](size_t bytes) {
    char* p = ws + off; off += (bytes + 255) & ~(size_t)255; return p;
  };
  unsigned short* ADJBF = (unsigned short*)alloc(512 * 512 * 2);
  unsigned short* ADJB  = (unsigned short*)alloc(512 * 512 * 2);
  unsigned short* W1T   = (unsigned short*)alloc(3 * 4096 * 2);
  unsigned short* W2T   = (unsigned short*)alloc(3 * 4096 * 2);
  float* SS1 = (float*)alloc(3 * 512 * 4);   // contiguous 4x6144B for one memset
  float* SQ1 = (float*)alloc(3 * 512 * 4);
  float* SS2 = (float*)alloc(3 * 512 * 4);
  float* SQ2 = (float*)alloc(3 * 512 * 4);
  float* A1  = (float*)alloc(3 * 512 * 4);
  float* C1  = (float*)alloc(3 * 512 * 4);
  float* RC  = (float*)alloc(512 * 4);
  float* SKIP = (float*)alloc(3 * 1024 * 64 * 4);
  float* OUTS = (float*)alloc(1024 * 192 * 4);
  unsigned short* AX  = (unsigned short*)alloc((size_t)1024 * 512 * 64 * 2);
  unsigned short* H1T = (unsigned short*)alloc((size_t)1024 * 64 * 512 * 2);
  unsigned short* H2T = (unsigned short*)alloc((size_t)1024 * 64 * 512 * 2);

  hipMemsetAsync(SS1, 0, 4 * 3 * 512 * 4, stream);

  k_prep_adj<<<1024, 256, 0, stream>>>(adj, ADJBF);
  k_prep_w<<<48, 256, 0, stream>>>(W1, W2, W1T, W2T);
  k_gemm_ax<<<1024, 256, 0, stream>>>(X, ADJBF, AX);

  for (int i = 0; i < 3; ++i) {
    k_h1<<<8192, 256, 0, stream>>>(AX, W1T + i * 4096, b1 + i * 64, H1T,
                                   SS1 + i * 512, SQ1 + i * 512);
    k_adjb<<<512, 256, 0, stream>>>(ADJBF, SS1 + i * 512, SQ1 + i * 512,
                                    g1 + i * 512, be1 + i * 512, ADJB, RC,
                                    A1 + i * 512, C1 + i * 512);
    k_minrow_skip<<<16384, 256, 0, stream>>>(H1T, A1 + i * 512, C1 + i * 512,
                                             SKIP + i * 65536);
    k_layer2<<<1024, 256, 0, stream>>>(H1T, ADJB, RC, W2T + i * 4096, b2 + i * 64, H2T);
    k_stats2<<<1024, 256, 0, stream>>>(H2T, SS2 + i * 512, SQ2 + i * 512);
    k_minrow_out<<<16384, 256, 0, stream>>>(H2T, SS2 + i * 512, SQ2 + i * 512,
                                            g2 + i * 512, be2 + i * 512,
                                            SKIP + i * 65536, OUTS, i);
  }
  k_fc<<<128, 256, 0, stream>>>(OUTS, Wfc, bfc, out);
}

// Round 5
// 716.166 us; speedup vs baseline: 3.3266x; 1.0617x over previous
//
#include <hip/hip_runtime.h>

// GNNTEP R5: adjacency GEMMs restructured: 128nx64 output tile per block,
// 8 waves, BK=64 double-buffered (8 phases, 64 MFMA/barrier-pair), grid =
// 1024b x 4 ntiles with bijective XCD swizzle (same-b tiles -> same XCD L2).
// A-operand (adjacency) is L2/L3-shared across blocks; LDS 48KB.
// layer2 keeps fused stage2 (W2 frags in regs, Gt reuses B-buffer).

typedef short  s16x8 __attribute__((ext_vector_type(8)));
typedef float  f32x4 __attribute__((ext_vector_type(4)));

#define NN   512
#define NB   1024
#define NH   64
#define LDT  72   // k_h1/transpose LDS row stride

#define MFMA16(a, b, c) __builtin_amdgcn_mfma_f32_16x16x32_bf16((a), (b), (c), 0, 0, 0)

#define GLOAD16(g, l) __builtin_amdgcn_global_load_lds( \
    (const __attribute__((address_space(1))) unsigned*)(g), \
    (__attribute__((address_space(3))) unsigned*)(l), 16, 0, 0)

__device__ __forceinline__ unsigned short f2bf(float f) {
  union { float f; unsigned u; } v; v.f = f;
  unsigned r = v.u + 0x7fffu + ((v.u >> 16) & 1u);   // RNE
  return (unsigned short)(r >> 16);
}
__device__ __forceinline__ float bf2f(unsigned short h) {
  union { unsigned u; float f; } v; v.u = ((unsigned)h) << 16;
  return v.f;
}

// ---------------- prep ----------------
__global__ void k_prep_adj(const float* __restrict__ adj, unsigned short* __restrict__ adjbf) {
  int idx = blockIdx.x * 256 + threadIdx.x;        // 512*512
  int n = idx >> 9, m = idx & 511;
  float v = adj[idx];
  if (n == m) v = 0.f;
  adjbf[idx] = f2bf(v);
}

// W1t[i][f][w] = W1[i][w][f];  W2t[i][d][f] = W2[i][f][d]
__global__ void k_prep_w(const float* __restrict__ W1, const float* __restrict__ W2,
                         unsigned short* __restrict__ W1t, unsigned short* __restrict__ W2t) {
  int idx = blockIdx.x * 256 + threadIdx.x;        // 3*64*64
  int i = idx >> 12, rc_ = idx & 4095;
  int src = (i << 12) + ((rc_ & 63) << 6) + (rc_ >> 6);
  W1t[idx] = f2bf(W1[src]);
  W2t[idx] = f2bf(W2[src]);
}

// X[b][m][w] f32 -> Xt[b][w][m] bf16 (per-block 64x64 tile via LDS)
__global__ __launch_bounds__(256)
void k_transpose_x(const float* __restrict__ X, unsigned short* __restrict__ Xt) {
  __shared__ unsigned short T[64 * LDT];
  int blk = blockIdx.x; int b = blk >> 3; int m0 = (blk & 7) << 6;
  int t = threadIdx.x; int r = t >> 2, seg = t & 3;
  const float* src = X + ((size_t)b * NN + m0 + r) * NH + seg * 16;
#pragma unroll
  for (int e = 0; e < 16; ++e) T[(seg * 16 + e) * LDT + r] = f2bf(src[e]);
  __syncthreads();
  unsigned short* dst = Xt + ((size_t)b * NH + r) * NN + m0 + seg * 16;
  const unsigned short* sT = &T[r * LDT + seg * 16];
  *(s16x8*)dst       = *(const s16x8*)sT;
  *(s16x8*)(dst + 8) = *(const s16x8*)(sT + 8);
}

// ---------------- AX = adj @ X : C[128n x 64w] per block ----------------
// A = Xt[b] rows w (k=m), B = adjbf rows n (k=m), D[i=w][j=n] -> AX[b][n][w]
__global__ __launch_bounds__(512)
void k_gemm_ax(const unsigned short* __restrict__ Xt, const unsigned short* __restrict__ adjbf,
               unsigned short* __restrict__ AX) {
  __shared__ unsigned short Ab[2][64 * 64];    // 8 KB each
  __shared__ unsigned short Bb[2][128 * 64];   // 16 KB each
  int h = blockIdx.x;
  int blk = (h & 7) * 512 + (h >> 3);          // bijective XCD swizzle (4096%8==0)
  int b = blk >> 2, n0 = (blk & 3) << 7;
  int t = threadIdx.x, lane = t & 63, wid = t >> 6;
  int wf = wid & 1, wn = wid >> 1;
  int arow = wid * 8 + (lane >> 3);            // 0..63 (= w)
  int brow0 = arow, brow1 = 64 + arow;         // n-local rows
  const unsigned short* aS  = Xt + ((size_t)b * NH + arow) * NN + (((lane & 7) ^ (arow & 7)) << 3);
  const unsigned short* bS0 = adjbf + (size_t)(n0 + brow0) * NN + (((lane & 7) ^ (brow0 & 7)) << 3);
  const unsigned short* bS1 = adjbf + (size_t)(n0 + brow1) * NN + (((lane & 7) ^ (brow1 & 7)) << 3);

  GLOAD16(aS,  &Ab[0][wid * 512]);
  GLOAD16(bS0, &Bb[0][wid * 512]);
  GLOAD16(bS1, &Bb[0][4096 + wid * 512]);
  __syncthreads();

  f32x4 acc[2][2] = {};
  for (int kt = 0; kt < 8; ++kt) {
    int cur = kt & 1;
    if (kt < 7) {
      int off = (kt + 1) * 64;
      GLOAD16(aS + off,  &Ab[cur ^ 1][wid * 512]);
      GLOAD16(bS0 + off, &Bb[cur ^ 1][wid * 512]);
      GLOAD16(bS1 + off, &Bb[cur ^ 1][4096 + wid * 512]);
    }
    const unsigned short* A = Ab[cur];
    const unsigned short* B = Bb[cur];
#pragma unroll
    for (int kk = 0; kk < 2; ++kk) {
      int ks = (kk * 32 + (lane >> 4) * 8) >> 3;           // k slot 0..7
      int ra0 = wf * 32 + (lane & 15), ra1 = ra0 + 16;
      int rb0 = wn * 32 + (lane & 15), rb1 = rb0 + 16;
      s16x8 a0 = *(const s16x8*)&A[ra0 * 64 + ((ks ^ (ra0 & 7)) << 3)];
      s16x8 a1 = *(const s16x8*)&A[ra1 * 64 + ((ks ^ (ra1 & 7)) << 3)];
      s16x8 b0 = *(const s16x8*)&B[rb0 * 64 + ((ks ^ (rb0 & 7)) << 3)];
      s16x8 b1 = *(const s16x8*)&B[rb1 * 64 + ((ks ^ (rb1 & 7)) << 3)];
      acc[0][0] = MFMA16(a0, b0, acc[0][0]);
      acc[1][0] = MFMA16(a1, b0, acc[1][0]);
      acc[0][1] = MFMA16(a0, b1, acc[0][1]);
      acc[1][1] = MFMA16(a1, b1, acc[1][1]);
    }
    __syncthreads();
  }
#pragma unroll
  for (int fi = 0; fi < 2; ++fi)
#pragma unroll
    for (int fj = 0; fj < 2; ++fj) {
      int n = n0 + wn * 32 + fj * 16 + (lane & 15);
      int w = wf * 32 + fi * 16 + (lane >> 4) * 4;
      ushort4 pk;
      pk.x = f2bf(acc[fi][fj][0]); pk.y = f2bf(acc[fi][fj][1]);
      pk.z = f2bf(acc[fi][fj][2]); pk.w = f2bf(acc[fi][fj][3]);
      *(ushort4*)&AX[((size_t)b * NN + n) * NH + w] = pk;
    }
}

// ---------------- H1t = relu(AX @ W1 + b1), + per-node stats ----------------
__global__ __launch_bounds__(256)
void k_h1(const unsigned short* __restrict__ AX, const unsigned short* __restrict__ W1t_i,
          const float* __restrict__ b1_i, unsigned short* __restrict__ H1t,
          float* __restrict__ Ssum, float* __restrict__ Ssq) {
  __shared__ unsigned short At[64 * LDT];
  __shared__ unsigned short Bw[64 * LDT];
  __shared__ float ssum[64], ssq[64];
  int blk = blockIdx.x; int b = blk >> 3; int n0 = (blk & 7) << 6;
  int t = threadIdx.x, lane = t & 63, wid = t >> 6;
  int wi = wid >> 1, wj = wid & 1;
  int r = t >> 2, seg = t & 3;
  if (t < 64) { ssum[t] = 0.f; ssq[t] = 0.f; }
  {
    const unsigned short* aSrc = AX + ((size_t)b * NN + n0 + r) * NH + seg * 16;
    const unsigned short* bSrc = W1t_i + r * 64 + seg * 16;
    *(s16x8*)&At[r * LDT + seg * 16] = *(const s16x8*)aSrc;
    *(s16x8*)&At[r * LDT + seg * 16 + 8] = *(const s16x8*)(aSrc + 8);
    *(s16x8*)&Bw[r * LDT + seg * 16] = *(const s16x8*)bSrc;
    *(s16x8*)&Bw[r * LDT + seg * 16 + 8] = *(const s16x8*)(bSrc + 8);
  }
  __syncthreads();
  f32x4 acc[2][2] = {};
#pragma unroll
  for (int kk = 0; kk < 2; ++kk) {
    int ko = kk * 32 + (lane >> 4) * 8;
    s16x8 a0 = *(const s16x8*)&At[(wi * 32 +  0 + (lane & 15)) * LDT + ko];
    s16x8 a1 = *(const s16x8*)&At[(wi * 32 + 16 + (lane & 15)) * LDT + ko];
    s16x8 b0 = *(const s16x8*)&Bw[(wj * 32 +  0 + (lane & 15)) * LDT + ko];
    s16x8 b1 = *(const s16x8*)&Bw[(wj * 32 + 16 + (lane & 15)) * LDT + ko];
    acc[0][0] = MFMA16(a0, b0, acc[0][0]);
    acc[1][0] = MFMA16(a1, b0, acc[1][0]);
    acc[0][1] = MFMA16(a0, b1, acc[0][1]);
    acc[1][1] = MFMA16(a1, b1, acc[1][1]);
  }
  int fcol = wj * 32 + (lane & 15);
  float bia0 = b1_i[fcol], bia1 = b1_i[fcol + 16];
#pragma unroll
  for (int fi = 0; fi < 2; ++fi) {
    int nloc = wi * 32 + fi * 16 + (lane >> 4) * 4;
    float v0[4], v1[4];
#pragma unroll
    for (int rr = 0; rr < 4; ++rr) {
      float x0 = fmaxf(acc[fi][0][rr] + bia0, 0.f);
      float x1 = fmaxf(acc[fi][1][rr] + bia1, 0.f);
      v0[rr] = x0; v1[rr] = x1;
      float sv = x0 + x1, qv = x0 * x0 + x1 * x1;
      sv += __shfl_xor(sv, 1); sv += __shfl_xor(sv, 2); sv += __shfl_xor(sv, 4); sv += __shfl_xor(sv, 8);
      qv += __shfl_xor(qv, 1); qv += __shfl_xor(qv, 2); qv += __shfl_xor(qv, 4); qv += __shfl_xor(qv, 8);
      if ((lane & 15) == 0) { atomicAdd(&ssum[nloc + rr], sv); atomicAdd(&ssq[nloc + rr], qv); }
    }
    ushort4 p0, p1;
    p0.x = f2bf(v0[0]); p0.y = f2bf(v0[1]); p0.z = f2bf(v0[2]); p0.w = f2bf(v0[3]);
    p1.x = f2bf(v1[0]); p1.y = f2bf(v1[1]); p1.z = f2bf(v1[2]); p1.w = f2bf(v1[3]);
    *(ushort4*)&H1t[((size_t)b * NH + fcol)      * NN + n0 + nloc] = p0;
    *(ushort4*)&H1t[((size_t)b * NH + fcol + 16) * NN + n0 + nloc] = p1;
  }
  __syncthreads();
  if (t < 64) { atomicAdd(&Ssum[n0 + t], ssum[t]); atomicAdd(&Ssq[n0 + t], ssq[t]); }
}

// ---------------- adjB = adj*a1[m]; rc[n] = sum adj[n][m]*c1[m]; BN1 inline ----------------
__global__ __launch_bounds__(256)
void k_adjb(const unsigned short* __restrict__ adjbf,
            const float* __restrict__ Ssum, const float* __restrict__ Ssq,
            const float* __restrict__ g, const float* __restrict__ be,
            unsigned short* __restrict__ adjB, float* __restrict__ rc,
            float* __restrict__ A1, float* __restrict__ C1) {
  __shared__ float red[256];
  int n = blockIdx.x, t = threadIdx.x;
  float acc = 0.f;
#pragma unroll
  for (int hh = 0; hh < 2; ++hh) {
    int m = t + hh * 256;
    float mean = Ssum[m] * (1.f / 65536.f);
    float var  = Ssq[m] * (1.f / 65536.f) - mean * mean;
    float a = g[m] * rsqrtf(var + 1e-5f);
    float c = be[m] - mean * a;
    if (n == 0) { A1[m] = a; C1[m] = c; }
    float av = bf2f(adjbf[n * NN + m]);
    adjB[n * NN + m] = f2bf(av * a);
    acc += av * c;
  }
  red[t] = acc; __syncthreads();
  for (int s = 128; s > 0; s >>= 1) { if (t < s) red[t] += red[t + s]; __syncthreads(); }
  if (t == 0) rc[n] = red[0];
}

// ---------------- skip-min: min over m of a1[m]*H1[m,f]+c1[m] ----------------
__global__ __launch_bounds__(256)
void k_minrow_skip(const unsigned short* __restrict__ Ht, const float* __restrict__ A1,
                   const float* __restrict__ C1, float* __restrict__ skip_i) {
  int t = threadIdx.x, lane = t & 63, wid = t >> 6;
  int row = blockIdx.x * 4 + wid;          // b*64 + f
  s16x8 hv = *(const s16x8*)(Ht + (size_t)row * NN + lane * 8);
  const float* ap = A1 + lane * 8;
  const float* cp = C1 + lane * 8;
  float m = 1e30f;
#pragma unroll
  for (int e = 0; e < 8; ++e) m = fminf(m, ap[e] * bf2f((unsigned short)hv[e]) + cp[e]);
#pragma unroll
  for (int off = 1; off < 64; off <<= 1) m = fminf(m, __shfl_xor(m, off));
  if (lane == 0) skip_i[row] = m;
}

// ---------------- BN2 stats over H2t (block per b, fire-and-forget flush) ----------------
__global__ __launch_bounds__(256)
void k_stats2(const unsigned short* __restrict__ H2t,
              float* __restrict__ Ssum, float* __restrict__ Ssq) {
  __shared__ float ls[512], lq[512];
  int b = blockIdx.x, t = threadIdx.x, lane = t & 63, wid = t >> 6;
  ls[t] = 0.f; ls[t + 256] = 0.f; lq[t] = 0.f; lq[t + 256] = 0.f;
  float s[8] = {}, q[8] = {};
  const unsigned short* base = H2t + (size_t)b * (NH * NN);
  for (int it = 0; it < 16; ++it) {
    int d = wid * 16 + it;
    s16x8 hv = *(const s16x8*)(base + (size_t)d * NN + lane * 8);
#pragma unroll
    for (int e = 0; e < 8; ++e) { float x = bf2f((unsigned short)hv[e]); s[e] += x; q[e] += x * x; }
  }
  __syncthreads();
#pragma unroll
  for (int e = 0; e < 8; ++e) {
    atomicAdd(&ls[lane * 8 + e], s[e]);
    atomicAdd(&lq[lane * 8 + e], q[e]);
  }
  __syncthreads();
  atomicAdd(&Ssum[t], ls[t]);       atomicAdd(&Ssum[t + 256], ls[t + 256]);
  atomicAdd(&Ssq[t],  lq[t]);       atomicAdd(&Ssq[t + 256],  lq[t + 256]);
}

// ---------------- min over n of a2[n]*h2+c2[n] (+skip), BN2 finalize inline ----------------
__global__ __launch_bounds__(256)
void k_minrow_out(const unsigned short* __restrict__ Ht,
                  const float* __restrict__ Ssum, const float* __restrict__ Ssq,
                  const float* __restrict__ g, const float* __restrict__ be,
                  const float* __restrict__ skip_i, float* __restrict__ outs, int i) {
  int t = threadIdx.x, lane = t & 63, wid = t >> 6;
  int row = blockIdx.x * 4 + wid;          // b*64 + d
  int b = row >> 6, d = row & 63;
  s16x8 hv = *(const s16x8*)(Ht + (size_t)row * NN + lane * 8);
  float m = 1e30f;
#pragma unroll
  for (int e = 0; e < 8; ++e) {
    int mm = lane * 8 + e;
    float mean = Ssum[mm] * (1.f / 65536.f);
    float var  = Ssq[mm] * (1.f / 65536.f) - mean * mean;
    float a = g[mm] * rsqrtf(var + 1e-5f);
    float c = be[mm] - mean * a;
    m = fminf(m, a * bf2f((unsigned short)hv[e]) + c);
  }
#pragma unroll
  for (int off = 1; off < 64; off <<= 1) m = fminf(m, __shfl_xor(m, off));
  if (lane == 0) outs[(size_t)b * 192 + i * 64 + d] = m + skip_i[row];
}

// ---------------- layer2: C[128n x 64] per block, fused stage2 ----------------
// stage1: A = H1t[b] rows f (k=m), B = adjB rows n (k=m), D1[i=f][j=n]
// Gt[n][f] = D1 + rc -> stage2: D2[i=n][j=d] = Gt @ W2t (regs), relu+b2 -> H2t[b][d][n]
__global__ __launch_bounds__(512)
void k_layer2(const unsigned short* __restrict__ H1t, const unsigned short* __restrict__ adjB,
              const float* __restrict__ rc, const unsigned short* __restrict__ W2t_i,
              const float* __restrict__ b2_i, unsigned short* __restrict__ H2t) {
  __shared__ unsigned short Ab[2][64 * 64];
  __shared__ unsigned short Bb[2][128 * 64];   // Bb[0] reused as Gt[n 128][f 64]
  int h = blockIdx.x;
  int blk = (h & 7) * 512 + (h >> 3);
  int b = blk >> 2, n0 = (blk & 3) << 7;
  int t = threadIdx.x, lane = t & 63, wid = t >> 6;
  int wf = wid & 1, wn = wid >> 1;
  int arow = wid * 8 + (lane >> 3);            // 0..63 (= f)
  int brow0 = arow, brow1 = 64 + arow;
  const unsigned short* aS  = H1t + ((size_t)b * NH + arow) * NN + (((lane & 7) ^ (arow & 7)) << 3);
  const unsigned short* bS0 = adjB + (size_t)(n0 + brow0) * NN + (((lane & 7) ^ (brow0 & 7)) << 3);
  const unsigned short* bS1 = adjB + (size_t)(n0 + brow1) * NN + (((lane & 7) ^ (brow1 & 7)) << 3);
  float rcv[2];
  rcv[0] = rc[n0 + wn * 32 + (lane & 15)];
  rcv[1] = rc[n0 + wn * 32 + 16 + (lane & 15)];

  GLOAD16(aS,  &Ab[0][wid * 512]);
  GLOAD16(bS0, &Bb[0][wid * 512]);
  GLOAD16(bS1, &Bb[0][4096 + wid * 512]);
  __syncthreads();

  f32x4 acc[2][2] = {};
  for (int kt = 0; kt < 8; ++kt) {
    int cur = kt & 1;
    if (kt < 7) {
      int off = (kt + 1) * 64;
      GLOAD16(aS + off,  &Ab[cur ^ 1][wid * 512]);
      GLOAD16(bS0 + off, &Bb[cur ^ 1][wid * 512]);
      GLOAD16(bS1 + off, &Bb[cur ^ 1][4096 + wid * 512]);
    }
    const unsigned short* A = Ab[cur];
    const unsigned short* B = Bb[cur];
#pragma unroll
    for (int kk = 0; kk < 2; ++kk) {
      int ks = (kk * 32 + (lane >> 4) * 8) >> 3;
      int ra0 = wf * 32 + (lane & 15), ra1 = ra0 + 16;
      int rb0 = wn * 32 + (lane & 15), rb1 = rb0 + 16;
      s16x8 a0 = *(const s16x8*)&A[ra0 * 64 + ((ks ^ (ra0 & 7)) << 3)];
      s16x8 a1 = *(const s16x8*)&A[ra1 * 64 + ((ks ^ (ra1 & 7)) << 3)];
      s16x8 b0 = *(const s16x8*)&B[rb0 * 64 + ((ks ^ (rb0 & 7)) << 3)];
      s16x8 b1 = *(const s16x8*)&B[rb1 * 64 + ((ks ^ (rb1 & 7)) << 3)];
      acc[0][0] = MFMA16(a0, b0, acc[0][0]);
      acc[1][0] = MFMA16(a1, b0, acc[1][0]);
      acc[0][1] = MFMA16(a0, b1, acc[0][1]);
      acc[1][1] = MFMA16(a1, b1, acc[1][1]);
    }
    __syncthreads();
  }
  // Gt[n][f] = D1[f][n] + rc[n] (swizzled store along f)
  unsigned short* Gt = Bb[0];
#pragma unroll
  for (int fi = 0; fi < 2; ++fi)
#pragma unroll
    for (int fj = 0; fj < 2; ++fj) {
      int n  = wn * 32 + fj * 16 + (lane & 15);
      int f0 = wf * 32 + fi * 16 + (lane >> 4) * 4;
      ushort4 p;
      p.x = f2bf(acc[fi][fj][0] + rcv[fj]); p.y = f2bf(acc[fi][fj][1] + rcv[fj]);
      p.z = f2bf(acc[fi][fj][2] + rcv[fj]); p.w = f2bf(acc[fi][fj][3] + rcv[fj]);
      *(ushort4*)&Gt[n * 64 + (((f0 >> 3) ^ (n & 7)) << 3) + (f0 & 7)] = p;
    }
  __syncthreads();
  // stage2: each wave handles 16 n-rows; W2 frags from global (L2-hot)
  s16x8 w2f[2][4];
  float bb[4];
#pragma unroll
  for (int kk = 0; kk < 2; ++kk)
#pragma unroll
    for (int fd = 0; fd < 4; ++fd)
      w2f[kk][fd] = *(const s16x8*)&W2t_i[(fd * 16 + (lane & 15)) * 64 + kk * 32 + (lane >> 4) * 8];
#pragma unroll
  for (int fd = 0; fd < 4; ++fd) bb[fd] = b2_i[fd * 16 + (lane & 15)];

  f32x4 acc2[4] = {};
#pragma unroll
  for (int kk = 0; kk < 2; ++kk) {
    int nrow = wid * 16 + (lane & 15);
    int es = (kk * 32 + (lane >> 4) * 8) >> 3;
    s16x8 a = *(const s16x8*)&Gt[nrow * 64 + ((es ^ (nrow & 7)) << 3)];
    acc2[0] = MFMA16(a, w2f[kk][0], acc2[0]);
    acc2[1] = MFMA16(a, w2f[kk][1], acc2[1]);
    acc2[2] = MFMA16(a, w2f[kk][2], acc2[2]);
    acc2[3] = MFMA16(a, w2f[kk][3], acc2[3]);
  }
#pragma unroll
  for (int fd = 0; fd < 4; ++fd) {
    int d  = fd * 16 + (lane & 15);
    int nw = n0 + wid * 16 + (lane >> 4) * 4;
    ushort4 p;
    p.x = f2bf(fmaxf(acc2[fd][0] + bb[fd], 0.f));
    p.y = f2bf(fmaxf(acc2[fd][1] + bb[fd], 0.f));
    p.z = f2bf(fmaxf(acc2[fd][2] + bb[fd], 0.f));
    p.w = f2bf(fmaxf(acc2[fd][3] + bb[fd], 0.f));
    *(ushort4*)&H2t[((size_t)b * NH + d) * NN + nw] = p;
  }
}

// ---------------- final FC ----------------
__global__ __launch_bounds__(256)
void k_fc(const float* __restrict__ outs, const float* __restrict__ Wfc,
          const float* __restrict__ bfc, float* __restrict__ out) {
  int t = threadIdx.x;
  int b = blockIdx.x * 8 + (t >> 5), o = t & 31;
  float acc = bfc[o];
  const float* orow = outs + (size_t)b * 192;
  for (int j = 0; j < 192; ++j) acc += orow[j] * Wfc[j * 32 + o];
  out[b * 32 + o] = acc;
}

extern "C" void kernel_launch(void* const* d_in, const int* in_sizes, int n_in,
                              void* d_out, int out_size, void* d_ws, size_t ws_size,
                              hipStream_t stream) {
  const float* X   = (const float*)d_in[0];
  const float* adj = (const float*)d_in[1];
  const float* W1  = (const float*)d_in[2];
  const float* b1  = (const float*)d_in[3];
  const float* g1  = (const float*)d_in[4];
  const float* be1 = (const float*)d_in[5];
  const float* W2  = (const float*)d_in[6];
  const float* b2  = (const float*)d_in[7];
  const float* g2  = (const float*)d_in[8];
  const float* be2 = (const float*)d_in[9];
  const float* Wfc = (const float*)d_in[10];
  const float* bfc = (const float*)d_in[11];
  float* out = (float*)d_out;

  char* ws = (char*)d_ws;
  size_t off = 0;
  auto alloc = [&](size_t bytes) {
    char* p = ws + off; off += (bytes + 255) & ~(size_t)255; return p;
  };
  unsigned short* ADJBF = (unsigned short*)alloc(512 * 512 * 2);
  unsigned short* ADJB  = (unsigned short*)alloc(512 * 512 * 2);
  unsigned short* W1T   = (unsigned short*)alloc(3 * 4096 * 2);
  unsigned short* W2T   = (unsigned short*)alloc(3 * 4096 * 2);
  float* SS1 = (float*)alloc(3 * 512 * 4);   // contiguous 4x6144B for one memset
  float* SQ1 = (float*)alloc(3 * 512 * 4);
  float* SS2 = (float*)alloc(3 * 512 * 4);
  float* SQ2 = (float*)alloc(3 * 512 * 4);
  float* A1  = (float*)alloc(3 * 512 * 4);
  float* C1  = (float*)alloc(3 * 512 * 4);
  float* RC  = (float*)alloc(512 * 4);
  float* SKIP = (float*)alloc(3 * 1024 * 64 * 4);
  float* OUTS = (float*)alloc(1024 * 192 * 4);
  unsigned short* XT  = (unsigned short*)alloc((size_t)1024 * 64 * 512 * 2);  // reused as H1T
  unsigned short* AX  = (unsigned short*)alloc((size_t)1024 * 512 * 64 * 2);
  unsigned short* H2T = (unsigned short*)alloc((size_t)1024 * 64 * 512 * 2);
  unsigned short* H1T = XT;   // Xt dead after k_gemm_ax

  hipMemsetAsync(SS1, 0, 4 * 3 * 512 * 4, stream);

  k_prep_adj<<<1024, 256, 0, stream>>>(adj, ADJBF);
  k_prep_w<<<48, 256, 0, stream>>>(W1, W2, W1T, W2T);
  k_transpose_x<<<8192, 256, 0, stream>>>(X, XT);
  k_gemm_ax<<<4096, 512, 0, stream>>>(XT, ADJBF, AX);

  for (int i = 0; i < 3; ++i) {
    k_h1<<<8192, 256, 0, stream>>>(AX, W1T + i * 4096, b1 + i * 64, H1T,
                                   SS1 + i * 512, SQ1 + i * 512);
    k_adjb<<<512, 256, 0, stream>>>(ADJBF, SS1 + i * 512, SQ1 + i * 512,
                                    g1 + i * 512, be1 + i * 512, ADJB, RC,
                                    A1 + i * 512, C1 + i * 512);
    k_minrow_skip<<<16384, 256, 0, stream>>>(H1T, A1 + i * 512, C1 + i * 512,
                                             SKIP + i * 65536);
    k_layer2<<<4096, 512, 0, stream>>>(H1T, ADJB, RC, W2T + i * 4096, b2 + i * 64, H2T);
    k_stats2<<<1024, 256, 0, stream>>>(H2T, SS2 + i * 512, SQ2 + i * 512);
    k_minrow_out<<<16384, 256, 0, stream>>>(H2T, SS2 + i * 512, SQ2 + i * 512,
                                            g2 + i * 512, be2 + i * 512,
                                            SKIP + i * 65536, OUTS, i);
  }
  k_fc<<<128, 256, 0, stream>>>(OUTS, Wfc, bfc, out);
}

// Round 6
// 668.645 us; speedup vs baseline: 3.5631x; 1.0711x over previous
//
#include <hip/hip_runtime.h>

// GNNTEP R6: three fusions on the R5 structure:
//  - k_gnn1 = gemm_ax + all 3 h1 projections (AX tensor eliminated; T tile in
//    LDS reusing B-buffer, 3x W1 staged in freed A-buffers; stats via
//    end-of-kernel fire-and-forget atomics, zero barriers in the h1 phase).
//  - k_layer2 += skip-min (n0==0 blocks, from staged A-tiles) and BN2 stats
//    (epilogue shuffle-reduce + end-of-kernel atomics).
// 23 -> 14 launches; ~450 MB less HBM traffic.

typedef short  s16x8 __attribute__((ext_vector_type(8)));
typedef float  f32x4 __attribute__((ext_vector_type(4)));

#define NN   512
#define NB   1024
#define NH   64
#define LDT  72

#define MFMA16(a, b, c) __builtin_amdgcn_mfma_f32_16x16x32_bf16((a), (b), (c), 0, 0, 0)

#define GLOAD16(g, l) __builtin_amdgcn_global_load_lds( \
    (const __attribute__((address_space(1))) unsigned*)(g), \
    (__attribute__((address_space(3))) unsigned*)(l), 16, 0, 0)

__device__ __forceinline__ unsigned short f2bf(float f) {
  union { float f; unsigned u; } v; v.f = f;
  unsigned r = v.u + 0x7fffu + ((v.u >> 16) & 1u);   // RNE
  return (unsigned short)(r >> 16);
}
__device__ __forceinline__ float bf2f(unsigned short h) {
  union { unsigned u; float f; } v; v.u = ((unsigned)h) << 16;
  return v.f;
}

// ---------------- prep ----------------
__global__ void k_prep_adj(const float* __restrict__ adj, unsigned short* __restrict__ adjbf) {
  int idx = blockIdx.x * 256 + threadIdx.x;        // 512*512
  int n = idx >> 9, m = idx & 511;
  float v = adj[idx];
  if (n == m) v = 0.f;
  adjbf[idx] = f2bf(v);
}

// W1t[i][f][w] = W1[i][w][f];  W2t[i][d][f] = W2[i][f][d]
__global__ void k_prep_w(const float* __restrict__ W1, const float* __restrict__ W2,
                         unsigned short* __restrict__ W1t, unsigned short* __restrict__ W2t) {
  int idx = blockIdx.x * 256 + threadIdx.x;        // 3*64*64
  int i = idx >> 12, rc_ = idx & 4095;
  int src = (i << 12) + ((rc_ & 63) << 6) + (rc_ >> 6);
  W1t[idx] = f2bf(W1[src]);
  W2t[idx] = f2bf(W2[src]);
}

// X[b][m][w] f32 -> Xt[b][w][m] bf16
__global__ __launch_bounds__(256)
void k_transpose_x(const float* __restrict__ X, unsigned short* __restrict__ Xt) {
  __shared__ unsigned short T[64 * LDT];
  int blk = blockIdx.x; int b = blk >> 3; int m0 = (blk & 7) << 6;
  int t = threadIdx.x; int r = t >> 2, seg = t & 3;
  const float* src = X + ((size_t)b * NN + m0 + r) * NH + seg * 16;
#pragma unroll
  for (int e = 0; e < 16; ++e) T[(seg * 16 + e) * LDT + r] = f2bf(src[e]);
  __syncthreads();
  unsigned short* dst = Xt + ((size_t)b * NH + r) * NN + m0 + seg * 16;
  const unsigned short* sT = &T[r * LDT + seg * 16];
  *(s16x8*)dst       = *(const s16x8*)sT;
  *(s16x8*)(dst + 8) = *(const s16x8*)(sT + 8);
}

// ---------------- k_gnn1: AX tile + 3x (AX@W1+b1, relu, stats1, H1T) ----------------
// stage1: A = Xt[b] rows w, B = adjbf rows n (128), D[w][n]; T[n][w] -> LDS.
// then: 3x D2[n][f] = T @ W1t[i]; relu+bias; stats1 atomics; H1T[i][b][f][n].
__global__ __launch_bounds__(512)
void k_gnn1(const unsigned short* __restrict__ Xt, const unsigned short* __restrict__ adjbf,
            const unsigned short* __restrict__ W1t, const float* __restrict__ b1,
            unsigned short* __restrict__ H1T, float* __restrict__ SS1, float* __restrict__ SQ1) {
  __shared__ unsigned short Ab[2][64 * 64];
  __shared__ unsigned short Bb[2][128 * 64];
  int h = blockIdx.x;
  int blk = (h & 7) * 512 + (h >> 3);
  int b = blk >> 2, n0 = (blk & 3) << 7;
  int t = threadIdx.x, lane = t & 63, wid = t >> 6;
  int wf = wid & 1, wn = wid >> 1;
  int arow = wid * 8 + (lane >> 3);
  int brow0 = arow, brow1 = 64 + arow;
  const unsigned short* aS  = Xt + ((size_t)b * NH + arow) * NN + (((lane & 7) ^ (arow & 7)) << 3);
  const unsigned short* bS0 = adjbf + (size_t)(n0 + brow0) * NN + (((lane & 7) ^ (brow0 & 7)) << 3);
  const unsigned short* bS1 = adjbf + (size_t)(n0 + brow1) * NN + (((lane & 7) ^ (brow1 & 7)) << 3);

  GLOAD16(aS,  &Ab[0][wid * 512]);
  GLOAD16(bS0, &Bb[0][wid * 512]);
  GLOAD16(bS1, &Bb[0][4096 + wid * 512]);
  __syncthreads();

  f32x4 acc[2][2] = {};
  for (int kt = 0; kt < 8; ++kt) {
    int cur = kt & 1;
    if (kt < 7) {
      int off = (kt + 1) * 64;
      GLOAD16(aS + off,  &Ab[cur ^ 1][wid * 512]);
      GLOAD16(bS0 + off, &Bb[cur ^ 1][wid * 512]);
      GLOAD16(bS1 + off, &Bb[cur ^ 1][4096 + wid * 512]);
    }
    const unsigned short* A = Ab[cur];
    const unsigned short* B = Bb[cur];
#pragma unroll
    for (int kk = 0; kk < 2; ++kk) {
      int ks = (kk * 32 + (lane >> 4) * 8) >> 3;
      int ra0 = wf * 32 + (lane & 15), ra1 = ra0 + 16;
      int rb0 = wn * 32 + (lane & 15), rb1 = rb0 + 16;
      s16x8 a0 = *(const s16x8*)&A[ra0 * 64 + ((ks ^ (ra0 & 7)) << 3)];
      s16x8 a1 = *(const s16x8*)&A[ra1 * 64 + ((ks ^ (ra1 & 7)) << 3)];
      s16x8 b0 = *(const s16x8*)&B[rb0 * 64 + ((ks ^ (rb0 & 7)) << 3)];
      s16x8 b1 = *(const s16x8*)&B[rb1 * 64 + ((ks ^ (rb1 & 7)) << 3)];
      acc[0][0] = MFMA16(a0, b0, acc[0][0]);
      acc[1][0] = MFMA16(a1, b0, acc[1][0]);
      acc[0][1] = MFMA16(a0, b1, acc[0][1]);
      acc[1][1] = MFMA16(a1, b1, acc[1][1]);
    }
    __syncthreads();
  }
  // T[n_local 128][w 64] (swizzled) into Bb[0]
  unsigned short* T = Bb[0];
#pragma unroll
  for (int fi = 0; fi < 2; ++fi)
#pragma unroll
    for (int fj = 0; fj < 2; ++fj) {
      int nl = wn * 32 + fj * 16 + (lane & 15);
      int w0 = wf * 32 + fi * 16 + (lane >> 4) * 4;
      ushort4 p;
      p.x = f2bf(acc[fi][fj][0]); p.y = f2bf(acc[fi][fj][1]);
      p.z = f2bf(acc[fi][fj][2]); p.w = f2bf(acc[fi][fj][3]);
      *(ushort4*)&T[nl * 64 + (((w0 >> 3) ^ (nl & 7)) << 3) + (w0 & 7)] = p;
    }
  // stage W1t[0..2] into Ab[0], Ab[1], Bb[1] (swizzled source)
#pragma unroll
  for (int j = 0; j < 3; ++j) {
    int task = wid + j * 8;                      // 0..23
    int ii = task >> 3, grp = task & 7;
    unsigned short* dstp = (ii == 0) ? &Ab[0][grp * 512]
                         : (ii == 1) ? &Ab[1][grp * 512] : &Bb[1][grp * 512];
    const unsigned short* gsrc = W1t + ii * 4096 + (grp * 8 + (lane >> 3)) * 64
                               + (((lane & 7) ^ (lane >> 3)) << 3);
    GLOAD16(gsrc, dstp);
  }
  __syncthreads();
  // 3x h1-GEMM (no barriers: T/W1 read-only)
  int nrow = wid * 16 + (lane & 15);
#pragma unroll
  for (int i = 0; i < 3; ++i) {
    const unsigned short* w1p = (i == 0) ? Ab[0] : (i == 1) ? Ab[1] : Bb[1];
    f32x4 acc2[4] = {};
#pragma unroll
    for (int kk = 0; kk < 2; ++kk) {
      int ks = (kk * 32 + (lane >> 4) * 8) >> 3;
      s16x8 a = *(const s16x8*)&T[nrow * 64 + ((ks ^ (nrow & 7)) << 3)];
#pragma unroll
      for (int fd = 0; fd < 4; ++fd) {
        int fr = fd * 16 + (lane & 15);
        s16x8 bw = *(const s16x8*)&w1p[fr * 64 + ((ks ^ (fr & 7)) << 3)];
        acc2[fd] = MFMA16(a, bw, acc2[fd]);
      }
    }
    unsigned short* H1i = H1T + (size_t)i * 33554432u;
    float svr[4] = {0.f, 0.f, 0.f, 0.f}, sqr[4] = {0.f, 0.f, 0.f, 0.f};
#pragma unroll
    for (int fd = 0; fd < 4; ++fd) {
      int f = fd * 16 + (lane & 15);
      float bia = b1[i * 64 + f];
      float x0 = fmaxf(acc2[fd][0] + bia, 0.f);
      float x1 = fmaxf(acc2[fd][1] + bia, 0.f);
      float x2 = fmaxf(acc2[fd][2] + bia, 0.f);
      float x3 = fmaxf(acc2[fd][3] + bia, 0.f);
      svr[0] += x0; svr[1] += x1; svr[2] += x2; svr[3] += x3;
      sqr[0] += x0 * x0; sqr[1] += x1 * x1; sqr[2] += x2 * x2; sqr[3] += x3 * x3;
      ushort4 p;
      p.x = f2bf(x0); p.y = f2bf(x1); p.z = f2bf(x2); p.w = f2bf(x3);
      *(ushort4*)&H1i[((size_t)b * NH + f) * NN + n0 + wid * 16 + (lane >> 4) * 4] = p;
    }
#pragma unroll
    for (int rr = 0; rr < 4; ++rr) {
      float sv = svr[rr], qv = sqr[rr];
      sv += __shfl_xor(sv, 1); sv += __shfl_xor(sv, 2); sv += __shfl_xor(sv, 4); sv += __shfl_xor(sv, 8);
      qv += __shfl_xor(qv, 1); qv += __shfl_xor(qv, 2); qv += __shfl_xor(qv, 4); qv += __shfl_xor(qv, 8);
      if ((lane & 15) == 0) {
        int n = n0 + wid * 16 + (lane >> 4) * 4 + rr;
        atomicAdd(&SS1[i * 512 + n], sv);
        atomicAdd(&SQ1[i * 512 + n], qv);
      }
    }
  }
}

// ---------------- adjB = adj*a1[m]; rc[n] = sum adj[n][m]*c1[m]; BN1 inline ----------------
__global__ __launch_bounds__(256)
void k_adjb(const unsigned short* __restrict__ adjbf,
            const float* __restrict__ Ssum, const float* __restrict__ Ssq,
            const float* __restrict__ g, const float* __restrict__ be,
            unsigned short* __restrict__ adjB, float* __restrict__ rc,
            float* __restrict__ A1, float* __restrict__ C1) {
  __shared__ float red[256];
  int n = blockIdx.x, t = threadIdx.x;
  float acc = 0.f;
#pragma unroll
  for (int hh = 0; hh < 2; ++hh) {
    int m = t + hh * 256;
    float mean = Ssum[m] * (1.f / 65536.f);
    float var  = Ssq[m] * (1.f / 65536.f) - mean * mean;
    float a = g[m] * rsqrtf(var + 1e-5f);
    float c = be[m] - mean * a;
    if (n == 0) { A1[m] = a; C1[m] = c; }
    float av = bf2f(adjbf[n * NN + m]);
    adjB[n * NN + m] = f2bf(av * a);
    acc += av * c;
  }
  red[t] = acc; __syncthreads();
  for (int s = 128; s > 0; s >>= 1) { if (t < s) red[t] += red[t + s]; __syncthreads(); }
  if (t == 0) rc[n] = red[0];
}

// ---------------- min over n of a2[n]*h2+c2[n] (+skip), BN2 finalize inline ----------------
__global__ __launch_bounds__(256)
void k_minrow_out(const unsigned short* __restrict__ Ht,
                  const float* __restrict__ Ssum, const float* __restrict__ Ssq,
                  const float* __restrict__ g, const float* __restrict__ be,
                  const float* __restrict__ skip_i, float* __restrict__ outs, int i) {
  int t = threadIdx.x, lane = t & 63, wid = t >> 6;
  int row = blockIdx.x * 4 + wid;          // b*64 + d
  int b = row >> 6, d = row & 63;
  s16x8 hv = *(const s16x8*)(Ht + (size_t)row * NN + lane * 8);
  float m = 1e30f;
#pragma unroll
  for (int e = 0; e < 8; ++e) {
    int mm = lane * 8 + e;
    float mean = Ssum[mm] * (1.f / 65536.f);
    float var  = Ssq[mm] * (1.f / 65536.f) - mean * mean;
    float a = g[mm] * rsqrtf(var + 1e-5f);
    float c = be[mm] - mean * a;
    m = fminf(m, a * bf2f((unsigned short)hv[e]) + c);
  }
#pragma unroll
  for (int off = 1; off < 64; off <<= 1) m = fminf(m, __shfl_xor(m, off));
  if (lane == 0) outs[(size_t)b * 192 + i * 64 + d] = m + skip_i[row];
}

// ---------------- layer2: 128n x 64 tile + fused stage2 + skip-min + stats2 ----------------
__global__ __launch_bounds__(512)
void k_layer2(const unsigned short* __restrict__ H1t_i, const unsigned short* __restrict__ adjB,
              const float* __restrict__ rc, const unsigned short* __restrict__ W2t_i,
              const float* __restrict__ b2_i, unsigned short* __restrict__ H2t,
              float* __restrict__ Ssum2, float* __restrict__ Ssq2,
              const float* __restrict__ A1v, const float* __restrict__ C1v,
              float* __restrict__ skip_i) {
  __shared__ unsigned short Ab[2][64 * 64];
  __shared__ unsigned short Bb[2][128 * 64];   // Bb[0] reused as Gt
  __shared__ float acs[512], ccs[512];
  int h = blockIdx.x;
  int blk = (h & 7) * 512 + (h >> 3);
  int b = blk >> 2, n0 = (blk & 3) << 7;
  int t = threadIdx.x, lane = t & 63, wid = t >> 6;
  int wf = wid & 1, wn = wid >> 1;
  bool do_min = (n0 == 0);
  int arow = wid * 8 + (lane >> 3);            // 0..63 (= f for A)
  int brow0 = arow, brow1 = 64 + arow;
  const unsigned short* aS  = H1t_i + ((size_t)b * NH + arow) * NN + (((lane & 7) ^ (arow & 7)) << 3);
  const unsigned short* bS0 = adjB + (size_t)(n0 + brow0) * NN + (((lane & 7) ^ (brow0 & 7)) << 3);
  const unsigned short* bS1 = adjB + (size_t)(n0 + brow1) * NN + (((lane & 7) ^ (brow1 & 7)) << 3);
  acs[t] = A1v[t]; ccs[t] = C1v[t];
  float rcv[2];
  rcv[0] = rc[n0 + wn * 32 + (lane & 15)];
  rcv[1] = rc[n0 + wn * 32 + 16 + (lane & 15)];

  GLOAD16(aS,  &Ab[0][wid * 512]);
  GLOAD16(bS0, &Bb[0][wid * 512]);
  GLOAD16(bS1, &Bb[0][4096 + wid * 512]);
  __syncthreads();

  float mn = 1e30f;
  f32x4 acc[2][2] = {};
  for (int kt = 0; kt < 8; ++kt) {
    int cur = kt & 1;
    if (kt < 7) {
      int off = (kt + 1) * 64;
      GLOAD16(aS + off,  &Ab[cur ^ 1][wid * 512]);
      GLOAD16(bS0 + off, &Bb[cur ^ 1][wid * 512]);
      GLOAD16(bS1 + off, &Bb[cur ^ 1][4096 + wid * 512]);
    }
    const unsigned short* A = Ab[cur];
    const unsigned short* B = Bb[cur];
    if (do_min) {
      // A rows are f; value at LDS slot s' = source slot s'^(f&7)
      int s2 = (lane & 7) ^ (arow & 7);
      s16x8 av = *(const s16x8*)&A[arow * 64 + (s2 << 3)];
      int m0 = kt * 64 + ((lane & 7) << 3);
#pragma unroll
      for (int e = 0; e < 8; ++e)
        mn = fminf(mn, acs[m0 + e] * bf2f((unsigned short)av[e]) + ccs[m0 + e]);
    }
#pragma unroll
    for (int kk = 0; kk < 2; ++kk) {
      int ks = (kk * 32 + (lane >> 4) * 8) >> 3;
      int ra0 = wf * 32 + (lane & 15), ra1 = ra0 + 16;
      int rb0 = wn * 32 + (lane & 15), rb1 = rb0 + 16;
      s16x8 a0 = *(const s16x8*)&A[ra0 * 64 + ((ks ^ (ra0 & 7)) << 3)];
      s16x8 a1 = *(const s16x8*)&A[ra1 * 64 + ((ks ^ (ra1 & 7)) << 3)];
      s16x8 b0 = *(const s16x8*)&B[rb0 * 64 + ((ks ^ (rb0 & 7)) << 3)];
      s16x8 b1 = *(const s16x8*)&B[rb1 * 64 + ((ks ^ (rb1 & 7)) << 3)];
      acc[0][0] = MFMA16(a0, b0, acc[0][0]);
      acc[1][0] = MFMA16(a1, b0, acc[1][0]);
      acc[0][1] = MFMA16(a0, b1, acc[0][1]);
      acc[1][1] = MFMA16(a1, b1, acc[1][1]);
    }
    __syncthreads();
  }
  if (do_min) {
    mn = fminf(mn, __shfl_xor(mn, 1));
    mn = fminf(mn, __shfl_xor(mn, 2));
    mn = fminf(mn, __shfl_xor(mn, 4));
    if ((lane & 7) == 0) skip_i[b * 64 + arow] = mn;   // f = arow
  }
  // Gt[n][f] = D1[f][n] + rc[n]
  unsigned short* Gt = Bb[0];
#pragma unroll
  for (int fi = 0; fi < 2; ++fi)
#pragma unroll
    for (int fj = 0; fj < 2; ++fj) {
      int n  = wn * 32 + fj * 16 + (lane & 15);
      int f0 = wf * 32 + fi * 16 + (lane >> 4) * 4;
      ushort4 p;
      p.x = f2bf(acc[fi][fj][0] + rcv[fj]); p.y = f2bf(acc[fi][fj][1] + rcv[fj]);
      p.z = f2bf(acc[fi][fj][2] + rcv[fj]); p.w = f2bf(acc[fi][fj][3] + rcv[fj]);
      *(ushort4*)&Gt[n * 64 + (((f0 >> 3) ^ (n & 7)) << 3) + (f0 & 7)] = p;
    }
  __syncthreads();
  // stage2: D2[n][d] = Gt @ W2t
  s16x8 w2f[2][4];
  float bb[4];
#pragma unroll
  for (int kk = 0; kk < 2; ++kk)
#pragma unroll
    for (int fd = 0; fd < 4; ++fd)
      w2f[kk][fd] = *(const s16x8*)&W2t_i[(fd * 16 + (lane & 15)) * 64 + kk * 32 + (lane >> 4) * 8];
#pragma unroll
  for (int fd = 0; fd < 4; ++fd) bb[fd] = b2_i[fd * 16 + (lane & 15)];

  f32x4 acc2[4] = {};
  int nrow = wid * 16 + (lane & 15);
#pragma unroll
  for (int kk = 0; kk < 2; ++kk) {
    int es = (kk * 32 + (lane >> 4) * 8) >> 3;
    s16x8 a = *(const s16x8*)&Gt[nrow * 64 + ((es ^ (nrow & 7)) << 3)];
    acc2[0] = MFMA16(a, w2f[kk][0], acc2[0]);
    acc2[1] = MFMA16(a, w2f[kk][1], acc2[1]);
    acc2[2] = MFMA16(a, w2f[kk][2], acc2[2]);
    acc2[3] = MFMA16(a, w2f[kk][3], acc2[3]);
  }
  float svr[4] = {0.f, 0.f, 0.f, 0.f}, sqr[4] = {0.f, 0.f, 0.f, 0.f};
#pragma unroll
  for (int fd = 0; fd < 4; ++fd) {
    int d  = fd * 16 + (lane & 15);
    int nw = n0 + wid * 16 + (lane >> 4) * 4;
    float x0 = fmaxf(acc2[fd][0] + bb[fd], 0.f);
    float x1 = fmaxf(acc2[fd][1] + bb[fd], 0.f);
    float x2 = fmaxf(acc2[fd][2] + bb[fd], 0.f);
    float x3 = fmaxf(acc2[fd][3] + bb[fd], 0.f);
    svr[0] += x0; svr[1] += x1; svr[2] += x2; svr[3] += x3;
    sqr[0] += x0 * x0; sqr[1] += x1 * x1; sqr[2] += x2 * x2; sqr[3] += x3 * x3;
    ushort4 p;
    p.x = f2bf(x0); p.y = f2bf(x1); p.z = f2bf(x2); p.w = f2bf(x3);
    *(ushort4*)&H2t[((size_t)b * NH + d) * NN + nw] = p;
  }
#pragma unroll
  for (int rr = 0; rr < 4; ++rr) {
    float sv = svr[rr], qv = sqr[rr];
    sv += __shfl_xor(sv, 1); sv += __shfl_xor(sv, 2); sv += __shfl_xor(sv, 4); sv += __shfl_xor(sv, 8);
    qv += __shfl_xor(qv, 1); qv += __shfl_xor(qv, 2); qv += __shfl_xor(qv, 4); qv += __shfl_xor(qv, 8);
    if ((lane & 15) == 0) {
      int n = n0 + wid * 16 + (lane >> 4) * 4 + rr;
      atomicAdd(&Ssum2[n], sv);
      atomicAdd(&Ssq2[n], qv);
    }
  }
}

// ---------------- final FC ----------------
__global__ __launch_bounds__(256)
void k_fc(const float* __restrict__ outs, const float* __restrict__ Wfc,
          const float* __restrict__ bfc, float* __restrict__ out) {
  int t = threadIdx.x;
  int b = blockIdx.x * 8 + (t >> 5), o = t & 31;
  float acc = bfc[o];
  const float* orow = outs + (size_t)b * 192;
  for (int j = 0; j < 192; ++j) acc += orow[j] * Wfc[j * 32 + o];
  out[b * 32 + o] = acc;
}

extern "C" void kernel_launch(void* const* d_in, const int* in_sizes, int n_in,
                              void* d_out, int out_size, void* d_ws, size_t ws_size,
                              hipStream_t stream) {
  const float* X   = (const float*)d_in[0];
  const float* adj = (const float*)d_in[1];
  const float* W1  = (const float*)d_in[2];
  const float* b1  = (const float*)d_in[3];
  const float* g1  = (const float*)d_in[4];
  const float* be1 = (const float*)d_in[5];
  const float* W2  = (const float*)d_in[6];
  const float* b2  = (const float*)d_in[7];
  const float* g2  = (const float*)d_in[8];
  const float* be2 = (const float*)d_in[9];
  const float* Wfc = (const float*)d_in[10];
  const float* bfc = (const float*)d_in[11];
  float* out = (float*)d_out;

  char* ws = (char*)d_ws;
  size_t off = 0;
  auto alloc = [&](size_t bytes) {
    char* p = ws + off; off += (bytes + 255) & ~(size_t)255; return p;
  };
  unsigned short* ADJBF = (unsigned short*)alloc(512 * 512 * 2);
  unsigned short* ADJB  = (unsigned short*)alloc(512 * 512 * 2);
  unsigned short* W1T   = (unsigned short*)alloc(3 * 4096 * 2);
  unsigned short* W2T   = (unsigned short*)alloc(3 * 4096 * 2);
  float* SS1 = (float*)alloc(3 * 512 * 4);   // contiguous 4x6144B for one memset
  float* SQ1 = (float*)alloc(3 * 512 * 4);
  float* SS2 = (float*)alloc(3 * 512 * 4);
  float* SQ2 = (float*)alloc(3 * 512 * 4);
  float* A1  = (float*)alloc(3 * 512 * 4);
  float* C1  = (float*)alloc(3 * 512 * 4);
  float* RC  = (float*)alloc(512 * 4);
  float* SKIP = (float*)alloc(3 * 1024 * 64 * 4);
  float* OUTS = (float*)alloc(1024 * 192 * 4);
  unsigned short* XT  = (unsigned short*)alloc((size_t)1024 * 64 * 512 * 2);  // reused as H2T
  unsigned short* H1T = (unsigned short*)alloc((size_t)3 * 1024 * 64 * 512 * 2);
  unsigned short* H2T = XT;   // Xt dead after k_gnn1; H2T first written in layer2(0)

  hipMemsetAsync(SS1, 0, 4 * 3 * 512 * 4, stream);

  k_prep_adj<<<1024, 256, 0, stream>>>(adj, ADJBF);
  k_prep_w<<<48, 256, 0, stream>>>(W1, W2, W1T, W2T);
  k_transpose_x<<<8192, 256, 0, stream>>>(X, XT);
  k_gnn1<<<4096, 512, 0, stream>>>(XT, ADJBF, W1T, b1, H1T, SS1, SQ1);

  for (int i = 0; i < 3; ++i) {
    k_adjb<<<512, 256, 0, stream>>>(ADJBF, SS1 + i * 512, SQ1 + i * 512,
                                    g1 + i * 512, be1 + i * 512, ADJB, RC,
                                    A1 + i * 512, C1 + i * 512);
    k_layer2<<<4096, 512, 0, stream>>>(H1T + (size_t)i * 33554432u, ADJB, RC,
                                       W2T + i * 4096, b2 + i * 64, H2T,
                                       SS2 + i * 512, SQ2 + i * 512,
                                       A1 + i * 512, C1 + i * 512, SKIP + i * 65536);
    k_minrow_out<<<16384, 256, 0, stream>>>(H2T, SS2 + i * 512, SQ2 + i * 512,
                                            g2 + i * 512, be2 + i * 512,
                                            SKIP + i * 65536, OUTS, i);
  }
  k_fc<<<128, 256, 0, stream>>>(OUTS, Wfc, bfc, out);
}

// Round 7
// 531.190 us; speedup vs baseline: 4.4851x; 1.2588x over previous
//
#include <hip/hip_runtime.h>

// GNNTEP R7: 2 batches per block in k_gnn1/k_layer2 (B-operand staged once,
// shared by both batches): MFMA/phase doubled, adj traffic + atomics halved.
// Grid 2048 = 512 b-pairs x 4 ntiles, bijective XCD swizzle. LDS 64-68KB.

typedef short  s16x8 __attribute__((ext_vector_type(8)));
typedef float  f32x4 __attribute__((ext_vector_type(4)));

#define NN   512
#define NB   1024
#define NH   64
#define LDT  72

#define MFMA16(a, b, c) __builtin_amdgcn_mfma_f32_16x16x32_bf16((a), (b), (c), 0, 0, 0)

#define GLOAD16(g, l) __builtin_amdgcn_global_load_lds( \
    (const __attribute__((address_space(1))) unsigned*)(g), \
    (__attribute__((address_space(3))) unsigned*)(l), 16, 0, 0)

__device__ __forceinline__ unsigned short f2bf(float f) {
  union { float f; unsigned u; } v; v.f = f;
  unsigned r = v.u + 0x7fffu + ((v.u >> 16) & 1u);   // RNE
  return (unsigned short)(r >> 16);
}
__device__ __forceinline__ float bf2f(unsigned short h) {
  union { unsigned u; float f; } v; v.u = ((unsigned)h) << 16;
  return v.f;
}

// ---------------- prep ----------------
__global__ void k_prep_adj(const float* __restrict__ adj, unsigned short* __restrict__ adjbf) {
  int idx = blockIdx.x * 256 + threadIdx.x;        // 512*512
  int n = idx >> 9, m = idx & 511;
  float v = adj[idx];
  if (n == m) v = 0.f;
  adjbf[idx] = f2bf(v);
}

// W1t[i][f][w] = W1[i][w][f];  W2t[i][d][f] = W2[i][f][d]
__global__ void k_prep_w(const float* __restrict__ W1, const float* __restrict__ W2,
                         unsigned short* __restrict__ W1t, unsigned short* __restrict__ W2t) {
  int idx = blockIdx.x * 256 + threadIdx.x;        // 3*64*64
  int i = idx >> 12, rc_ = idx & 4095;
  int src = (i << 12) + ((rc_ & 63) << 6) + (rc_ >> 6);
  W1t[idx] = f2bf(W1[src]);
  W2t[idx] = f2bf(W2[src]);
}

// X[b][m][w] f32 -> Xt[b][w][m] bf16
__global__ __launch_bounds__(256)
void k_transpose_x(const float* __restrict__ X, unsigned short* __restrict__ Xt) {
  __shared__ unsigned short T[64 * LDT];
  int blk = blockIdx.x; int b = blk >> 3; int m0 = (blk & 7) << 6;
  int t = threadIdx.x; int r = t >> 2, seg = t & 3;
  const float* src = X + ((size_t)b * NN + m0 + r) * NH + seg * 16;
#pragma unroll
  for (int e = 0; e < 16; ++e) T[(seg * 16 + e) * LDT + r] = f2bf(src[e]);
  __syncthreads();
  unsigned short* dst = Xt + ((size_t)b * NH + r) * NN + m0 + seg * 16;
  const unsigned short* sT = &T[r * LDT + seg * 16];
  *(s16x8*)dst       = *(const s16x8*)sT;
  *(s16x8*)(dst + 8) = *(const s16x8*)(sT + 8);
}

// ---------------- k_gnn1: 2-batch AX tile + 3x h1 projections + stats1 ----------------
__global__ __launch_bounds__(512)
void k_gnn1(const unsigned short* __restrict__ Xt, const unsigned short* __restrict__ adjbf,
            const unsigned short* __restrict__ W1t, const float* __restrict__ b1,
            unsigned short* __restrict__ H1T, float* __restrict__ SS1, float* __restrict__ SQ1) {
  __shared__ unsigned short Ab[2][2][4096];    // [b][dbuf] 32 KB
  __shared__ unsigned short Bb[2][8192];       // [dbuf]    32 KB; reused as T0/T1
  int h = blockIdx.x;
  int blk = (h & 7) * 256 + (h >> 3);          // bijective (2048 % 8 == 0)
  int bp = blk >> 2, n0 = (blk & 3) << 7;
  int b0 = bp * 2, b1v = bp * 2 + 1;
  int t = threadIdx.x, lane = t & 63, wid = t >> 6;
  int wf = wid & 1, wn = wid >> 1;
  int arow = wid * 8 + (lane >> 3);            // 0..63 (= w)
  int swz = ((lane & 7) ^ (arow & 7)) << 3;
  const unsigned short* aS0 = Xt + ((size_t)b0  * NH + arow) * NN + swz;
  const unsigned short* aS1 = Xt + ((size_t)b1v * NH + arow) * NN + swz;
  const unsigned short* bS0 = adjbf + (size_t)(n0 + arow) * NN + swz;
  const unsigned short* bS1 = adjbf + (size_t)(n0 + 64 + arow) * NN + swz;

  GLOAD16(aS0, &Ab[0][0][wid * 512]);
  GLOAD16(aS1, &Ab[1][0][wid * 512]);
  GLOAD16(bS0, &Bb[0][wid * 512]);
  GLOAD16(bS1, &Bb[0][4096 + wid * 512]);
  __syncthreads();

  f32x4 acc[2][2][2] = {};
  for (int kt = 0; kt < 8; ++kt) {
    int cur = kt & 1;
    if (kt < 7) {
      int off = (kt + 1) * 64;
      GLOAD16(aS0 + off, &Ab[0][cur ^ 1][wid * 512]);
      GLOAD16(aS1 + off, &Ab[1][cur ^ 1][wid * 512]);
      GLOAD16(bS0 + off, &Bb[cur ^ 1][wid * 512]);
      GLOAD16(bS1 + off, &Bb[cur ^ 1][4096 + wid * 512]);
    }
    const unsigned short* B = Bb[cur];
#pragma unroll
    for (int kk = 0; kk < 2; ++kk) {
      int ks = (lane >> 4) + kk * 4;                       // k-slot 0..7
      int ra0 = wf * 32 + (lane & 15), ra1 = ra0 + 16;
      int rb0 = wn * 32 + (lane & 15), rb1 = rb0 + 16;
      s16x8 bf0 = *(const s16x8*)&B[rb0 * 64 + ((ks ^ (rb0 & 7)) << 3)];
      s16x8 bf1 = *(const s16x8*)&B[rb1 * 64 + ((ks ^ (rb1 & 7)) << 3)];
#pragma unroll
      for (int bs = 0; bs < 2; ++bs) {
        const unsigned short* A = Ab[bs][cur];
        s16x8 a0 = *(const s16x8*)&A[ra0 * 64 + ((ks ^ (ra0 & 7)) << 3)];
        s16x8 a1 = *(const s16x8*)&A[ra1 * 64 + ((ks ^ (ra1 & 7)) << 3)];
        acc[bs][0][0] = MFMA16(a0, bf0, acc[bs][0][0]);
        acc[bs][1][0] = MFMA16(a1, bf0, acc[bs][1][0]);
        acc[bs][0][1] = MFMA16(a0, bf1, acc[bs][0][1]);
        acc[bs][1][1] = MFMA16(a1, bf1, acc[bs][1][1]);
      }
    }
    __syncthreads();
  }
  // T_b[n 128][w 64] (swizzled): T0 = Bb[0], T1 = Bb[1]
#pragma unroll
  for (int bs = 0; bs < 2; ++bs) {
    unsigned short* T = Bb[bs];
#pragma unroll
    for (int fi = 0; fi < 2; ++fi)
#pragma unroll
      for (int fj = 0; fj < 2; ++fj) {
        int nl = wn * 32 + fj * 16 + (lane & 15);
        int w0 = wf * 32 + fi * 16 + (lane >> 4) * 4;
        ushort4 p;
        p.x = f2bf(acc[bs][fi][fj][0]); p.y = f2bf(acc[bs][fi][fj][1]);
        p.z = f2bf(acc[bs][fi][fj][2]); p.w = f2bf(acc[bs][fi][fj][3]);
        *(ushort4*)&T[nl * 64 + (((w0 >> 3) ^ (nl & 7)) << 3) + (w0 & 7)] = p;
      }
  }
  // stage 3x W1 into Ab[0][0], Ab[0][1], Ab[1][0]
#pragma unroll
  for (int j = 0; j < 3; ++j) {
    unsigned short* dstp = (j == 0) ? &Ab[0][0][wid * 512]
                         : (j == 1) ? &Ab[0][1][wid * 512] : &Ab[1][0][wid * 512];
    const unsigned short* gsrc = W1t + j * 4096 + (wid * 8 + (lane >> 3)) * 64
                               + (((lane & 7) ^ (lane >> 3)) << 3);
    GLOAD16(gsrc, dstp);
  }
  __syncthreads();
  // h1 phase: D2[n][f] = T_b @ W1t[i]
  int nrow = wid * 16 + (lane & 15);
  s16x8 aT[2][2];
#pragma unroll
  for (int bs = 0; bs < 2; ++bs)
#pragma unroll
    for (int kk = 0; kk < 2; ++kk) {
      int ks = (lane >> 4) + kk * 4;
      aT[bs][kk] = *(const s16x8*)&Bb[bs][nrow * 64 + ((ks ^ (nrow & 7)) << 3)];
    }
#pragma unroll
  for (int i = 0; i < 3; ++i) {
    const unsigned short* w1p = (i == 0) ? Ab[0][0] : (i == 1) ? Ab[0][1] : Ab[1][0];
    s16x8 bw[2][4];
#pragma unroll
    for (int kk = 0; kk < 2; ++kk) {
      int ks = (lane >> 4) + kk * 4;
#pragma unroll
      for (int fd = 0; fd < 4; ++fd) {
        int fr = fd * 16 + (lane & 15);
        bw[kk][fd] = *(const s16x8*)&w1p[fr * 64 + ((ks ^ (fr & 7)) << 3)];
      }
    }
    f32x4 acc2[2][4] = {};
#pragma unroll
    for (int bs = 0; bs < 2; ++bs)
#pragma unroll
      for (int kk = 0; kk < 2; ++kk) {
        acc2[bs][0] = MFMA16(aT[bs][kk], bw[kk][0], acc2[bs][0]);
        acc2[bs][1] = MFMA16(aT[bs][kk], bw[kk][1], acc2[bs][1]);
        acc2[bs][2] = MFMA16(aT[bs][kk], bw[kk][2], acc2[bs][2]);
        acc2[bs][3] = MFMA16(aT[bs][kk], bw[kk][3], acc2[bs][3]);
      }
    unsigned short* H1i = H1T + (size_t)i * 33554432u;
    float svr[4] = {0.f, 0.f, 0.f, 0.f}, sqr[4] = {0.f, 0.f, 0.f, 0.f};
#pragma unroll
    for (int bs = 0; bs < 2; ++bs) {
      int bcur = bs == 0 ? b0 : b1v;
#pragma unroll
      for (int fd = 0; fd < 4; ++fd) {
        int f = fd * 16 + (lane & 15);
        float bia = b1[i * 64 + f];
        float x0 = fmaxf(acc2[bs][fd][0] + bia, 0.f);
        float x1 = fmaxf(acc2[bs][fd][1] + bia, 0.f);
        float x2 = fmaxf(acc2[bs][fd][2] + bia, 0.f);
        float x3 = fmaxf(acc2[bs][fd][3] + bia, 0.f);
        svr[0] += x0; svr[1] += x1; svr[2] += x2; svr[3] += x3;
        sqr[0] += x0 * x0; sqr[1] += x1 * x1; sqr[2] += x2 * x2; sqr[3] += x3 * x3;
        ushort4 p;
        p.x = f2bf(x0); p.y = f2bf(x1); p.z = f2bf(x2); p.w = f2bf(x3);
        *(ushort4*)&H1i[((size_t)bcur * NH + f) * NN + n0 + nrow - (lane & 15) + (lane >> 4) * 4] = p;
      }
    }
#pragma unroll
    for (int rr = 0; rr < 4; ++rr) {
      float sv = svr[rr], qv = sqr[rr];
      sv += __shfl_xor(sv, 1); sv += __shfl_xor(sv, 2); sv += __shfl_xor(sv, 4); sv += __shfl_xor(sv, 8);
      qv += __shfl_xor(qv, 1); qv += __shfl_xor(qv, 2); qv += __shfl_xor(qv, 4); qv += __shfl_xor(qv, 8);
      if ((lane & 15) == 0) {
        int n = n0 + wid * 16 + (lane >> 4) * 4 + rr;
        atomicAdd(&SS1[i * 512 + n], sv);
        atomicAdd(&SQ1[i * 512 + n], qv);
      }
    }
  }
}

// ---------------- adjB = adj*a1[m]; rc[n] = sum adj[n][m]*c1[m]; BN1 inline ----------------
__global__ __launch_bounds__(256)
void k_adjb(const unsigned short* __restrict__ adjbf,
            const float* __restrict__ Ssum, const float* __restrict__ Ssq,
            const float* __restrict__ g, const float* __restrict__ be,
            unsigned short* __restrict__ adjB, float* __restrict__ rc,
            float* __restrict__ A1, float* __restrict__ C1) {
  __shared__ float red[256];
  int n = blockIdx.x, t = threadIdx.x;
  float acc = 0.f;
#pragma unroll
  for (int hh = 0; hh < 2; ++hh) {
    int m = t + hh * 256;
    float mean = Ssum[m] * (1.f / 65536.f);
    float var  = Ssq[m] * (1.f / 65536.f) - mean * mean;
    float a = g[m] * rsqrtf(var + 1e-5f);
    float c = be[m] - mean * a;
    if (n == 0) { A1[m] = a; C1[m] = c; }
    float av = bf2f(adjbf[n * NN + m]);
    adjB[n * NN + m] = f2bf(av * a);
    acc += av * c;
  }
  red[t] = acc; __syncthreads();
  for (int s = 128; s > 0; s >>= 1) { if (t < s) red[t] += red[t + s]; __syncthreads(); }
  if (t == 0) rc[n] = red[0];
}

// ---------------- min over n of a2[n]*h2+c2[n] (+skip), BN2 finalize inline ----------------
__global__ __launch_bounds__(256)
void k_minrow_out(const unsigned short* __restrict__ Ht,
                  const float* __restrict__ Ssum, const float* __restrict__ Ssq,
                  const float* __restrict__ g, const float* __restrict__ be,
                  const float* __restrict__ skip_i, float* __restrict__ outs, int i) {
  int t = threadIdx.x, lane = t & 63, wid = t >> 6;
  int row = blockIdx.x * 4 + wid;          // b*64 + d
  int b = row >> 6, d = row & 63;
  s16x8 hv = *(const s16x8*)(Ht + (size_t)row * NN + lane * 8);
  float m = 1e30f;
#pragma unroll
  for (int e = 0; e < 8; ++e) {
    int mm = lane * 8 + e;
    float mean = Ssum[mm] * (1.f / 65536.f);
    float var  = Ssq[mm] * (1.f / 65536.f) - mean * mean;
    float a = g[mm] * rsqrtf(var + 1e-5f);
    float c = be[mm] - mean * a;
    m = fminf(m, a * bf2f((unsigned short)hv[e]) + c);
  }
#pragma unroll
  for (int off = 1; off < 64; off <<= 1) m = fminf(m, __shfl_xor(m, off));
  if (lane == 0) outs[(size_t)b * 192 + i * 64 + d] = m + skip_i[row];
}

// ---------------- layer2: 2-batch, fused stage2 + skip-min + stats2 ----------------
__global__ __launch_bounds__(512)
void k_layer2(const unsigned short* __restrict__ H1t_i, const unsigned short* __restrict__ adjB,
              const float* __restrict__ rc, const unsigned short* __restrict__ W2t_i,
              const float* __restrict__ b2_i, unsigned short* __restrict__ H2t,
              float* __restrict__ Ssum2, float* __restrict__ Ssq2,
              const float* __restrict__ A1v, const float* __restrict__ C1v,
              float* __restrict__ skip_i) {
  __shared__ unsigned short Ab[2][2][4096];    // [b][dbuf] 32 KB
  __shared__ unsigned short Bb[2][8192];       // 32 KB; reused as Gt0/Gt1
  __shared__ float acs[512], ccs[512];
  int h = blockIdx.x;
  int blk = (h & 7) * 256 + (h >> 3);
  int bp = blk >> 2, n0 = (blk & 3) << 7;
  int b0 = bp * 2, b1v = bp * 2 + 1;
  int t = threadIdx.x, lane = t & 63, wid = t >> 6;
  int wf = wid & 1, wn = wid >> 1;
  bool do_min = (n0 == 0);
  int arow = wid * 8 + (lane >> 3);            // 0..63 (= f)
  int swz = ((lane & 7) ^ (arow & 7)) << 3;
  const unsigned short* aS0 = H1t_i + ((size_t)b0  * NH + arow) * NN + swz;
  const unsigned short* aS1 = H1t_i + ((size_t)b1v * NH + arow) * NN + swz;
  const unsigned short* bS0 = adjB + (size_t)(n0 + arow) * NN + swz;
  const unsigned short* bS1 = adjB + (size_t)(n0 + 64 + arow) * NN + swz;
  acs[t] = A1v[t]; ccs[t] = C1v[t];
  float rcv[2];
  rcv[0] = rc[n0 + wn * 32 + (lane & 15)];
  rcv[1] = rc[n0 + wn * 32 + 16 + (lane & 15)];

  GLOAD16(aS0, &Ab[0][0][wid * 512]);
  GLOAD16(aS1, &Ab[1][0][wid * 512]);
  GLOAD16(bS0, &Bb[0][wid * 512]);
  GLOAD16(bS1, &Bb[0][4096 + wid * 512]);
  __syncthreads();

  float mn0 = 1e30f, mn1 = 1e30f;
  f32x4 acc[2][2][2] = {};
  for (int kt = 0; kt < 8; ++kt) {
    int cur = kt & 1;
    if (kt < 7) {
      int off = (kt + 1) * 64;
      GLOAD16(aS0 + off, &Ab[0][cur ^ 1][wid * 512]);
      GLOAD16(aS1 + off, &Ab[1][cur ^ 1][wid * 512]);
      GLOAD16(bS0 + off, &Bb[cur ^ 1][wid * 512]);
      GLOAD16(bS1 + off, &Bb[cur ^ 1][4096 + wid * 512]);
    }
    if (do_min) {
      int s2 = ((lane & 7) ^ (arow & 7)) << 3;
      s16x8 av0 = *(const s16x8*)&Ab[0][cur][arow * 64 + s2];
      s16x8 av1 = *(const s16x8*)&Ab[1][cur][arow * 64 + s2];
      int m0 = kt * 64 + ((lane & 7) << 3);
#pragma unroll
      for (int e = 0; e < 8; ++e) {
        mn0 = fminf(mn0, acs[m0 + e] * bf2f((unsigned short)av0[e]) + ccs[m0 + e]);
        mn1 = fminf(mn1, acs[m0 + e] * bf2f((unsigned short)av1[e]) + ccs[m0 + e]);
      }
    }
    const unsigned short* B = Bb[cur];
#pragma unroll
    for (int kk = 0; kk < 2; ++kk) {
      int ks = (lane >> 4) + kk * 4;
      int ra0 = wf * 32 + (lane & 15), ra1 = ra0 + 16;
      int rb0 = wn * 32 + (lane & 15), rb1 = rb0 + 16;
      s16x8 bf0 = *(const s16x8*)&B[rb0 * 64 + ((ks ^ (rb0 & 7)) << 3)];
      s16x8 bf1 = *(const s16x8*)&B[rb1 * 64 + ((ks ^ (rb1 & 7)) << 3)];
#pragma unroll
      for (int bs = 0; bs < 2; ++bs) {
        const unsigned short* A = Ab[bs][cur];
        s16x8 a0 = *(const s16x8*)&A[ra0 * 64 + ((ks ^ (ra0 & 7)) << 3)];
        s16x8 a1 = *(const s16x8*)&A[ra1 * 64 + ((ks ^ (ra1 & 7)) << 3)];
        acc[bs][0][0] = MFMA16(a0, bf0, acc[bs][0][0]);
        acc[bs][1][0] = MFMA16(a1, bf0, acc[bs][1][0]);
        acc[bs][0][1] = MFMA16(a0, bf1, acc[bs][0][1]);
        acc[bs][1][1] = MFMA16(a1, bf1, acc[bs][1][1]);
      }
    }
    __syncthreads();
  }
  if (do_min) {
    mn0 = fminf(mn0, __shfl_xor(mn0, 1)); mn1 = fminf(mn1, __shfl_xor(mn1, 1));
    mn0 = fminf(mn0, __shfl_xor(mn0, 2)); mn1 = fminf(mn1, __shfl_xor(mn1, 2));
    mn0 = fminf(mn0, __shfl_xor(mn0, 4)); mn1 = fminf(mn1, __shfl_xor(mn1, 4));
    if ((lane & 7) == 0) {
      skip_i[b0 * 64 + arow] = mn0;
      skip_i[b1v * 64 + arow] = mn1;
    }
  }
  // Gt_b[n][f] = D1[f][n] + rc[n]
#pragma unroll
  for (int bs = 0; bs < 2; ++bs) {
    unsigned short* Gt = Bb[bs];
#pragma unroll
    for (int fi = 0; fi < 2; ++fi)
#pragma unroll
      for (int fj = 0; fj < 2; ++fj) {
        int n  = wn * 32 + fj * 16 + (lane & 15);
        int f0 = wf * 32 + fi * 16 + (lane >> 4) * 4;
        ushort4 p;
        p.x = f2bf(acc[bs][fi][fj][0] + rcv[fj]); p.y = f2bf(acc[bs][fi][fj][1] + rcv[fj]);
        p.z = f2bf(acc[bs][fi][fj][2] + rcv[fj]); p.w = f2bf(acc[bs][fi][fj][3] + rcv[fj]);
        *(ushort4*)&Gt[n * 64 + (((f0 >> 3) ^ (n & 7)) << 3) + (f0 & 7)] = p;
      }
  }
  __syncthreads();
  // stage2: D2[n][d] = Gt_b @ W2t (W2 frags shared across b)
  s16x8 w2f[2][4];
  float bb[4];
#pragma unroll
  for (int kk = 0; kk < 2; ++kk)
#pragma unroll
    for (int fd = 0; fd < 4; ++fd)
      w2f[kk][fd] = *(const s16x8*)&W2t_i[(fd * 16 + (lane & 15)) * 64 + kk * 32 + (lane >> 4) * 8];
#pragma unroll
  for (int fd = 0; fd < 4; ++fd) bb[fd] = b2_i[fd * 16 + (lane & 15)];

  int nrow = wid * 16 + (lane & 15);
  f32x4 acc2[2][4] = {};
#pragma unroll
  for (int bs = 0; bs < 2; ++bs)
#pragma unroll
    for (int kk = 0; kk < 2; ++kk) {
      int ks = (lane >> 4) + kk * 4;
      s16x8 a = *(const s16x8*)&Bb[bs][nrow * 64 + ((ks ^ (nrow & 7)) << 3)];
      acc2[bs][0] = MFMA16(a, w2f[kk][0], acc2[bs][0]);
      acc2[bs][1] = MFMA16(a, w2f[kk][1], acc2[bs][1]);
      acc2[bs][2] = MFMA16(a, w2f[kk][2], acc2[bs][2]);
      acc2[bs][3] = MFMA16(a, w2f[kk][3], acc2[bs][3]);
    }
  float svr[4] = {0.f, 0.f, 0.f, 0.f}, sqr[4] = {0.f, 0.f, 0.f, 0.f};
#pragma unroll
  for (int bs = 0; bs < 2; ++bs) {
    int bcur = bs == 0 ? b0 : b1v;
#pragma unroll
    for (int fd = 0; fd < 4; ++fd) {
      int d  = fd * 16 + (lane & 15);
      int nw = n0 + wid * 16 + (lane >> 4) * 4;
      float x0 = fmaxf(acc2[bs][fd][0] + bb[fd], 0.f);
      float x1 = fmaxf(acc2[bs][fd][1] + bb[fd], 0.f);
      float x2 = fmaxf(acc2[bs][fd][2] + bb[fd], 0.f);
      float x3 = fmaxf(acc2[bs][fd][3] + bb[fd], 0.f);
      svr[0] += x0; svr[1] += x1; svr[2] += x2; svr[3] += x3;
      sqr[0] += x0 * x0; sqr[1] += x1 * x1; sqr[2] += x2 * x2; sqr[3] += x3 * x3;
      ushort4 p;
      p.x = f2bf(x0); p.y = f2bf(x1); p.z = f2bf(x2); p.w = f2bf(x3);
      *(ushort4*)&H2t[((size_t)bcur * NH + d) * NN + nw] = p;
    }
  }
#pragma unroll
  for (int rr = 0; rr < 4; ++rr) {
    float sv = svr[rr], qv = sqr[rr];
    sv += __shfl_xor(sv, 1); sv += __shfl_xor(sv, 2); sv += __shfl_xor(sv, 4); sv += __shfl_xor(sv, 8);
    qv += __shfl_xor(qv, 1); qv += __shfl_xor(qv, 2); qv += __shfl_xor(qv, 4); qv += __shfl_xor(qv, 8);
    if ((lane & 15) == 0) {
      int n = n0 + wid * 16 + (lane >> 4) * 4 + rr;
      atomicAdd(&Ssum2[n], sv);
      atomicAdd(&Ssq2[n], qv);
    }
  }
}

// ---------------- final FC ----------------
__global__ __launch_bounds__(256)
void k_fc(const float* __restrict__ outs, const float* __restrict__ Wfc,
          const float* __restrict__ bfc, float* __restrict__ out) {
  int t = threadIdx.x;
  int b = blockIdx.x * 8 + (t >> 5), o = t & 31;
  float acc = bfc[o];
  const float* orow = outs + (size_t)b * 192;
  for (int j = 0; j < 192; ++j) acc += orow[j] * Wfc[j * 32 + o];
  out[b * 32 + o] = acc;
}

extern "C" void kernel_launch(void* const* d_in, const int* in_sizes, int n_in,
                              void* d_out, int out_size, void* d_ws, size_t ws_size,
                              hipStream_t stream) {
  const float* X   = (const float*)d_in[0];
  const float* adj = (const float*)d_in[1];
  const float* W1  = (const float*)d_in[2];
  const float* b1  = (const float*)d_in[3];
  const float* g1  = (const float*)d_in[4];
  const float* be1 = (const float*)d_in[5];
  const float* W2  = (const float*)d_in[6];
  const float* b2  = (const float*)d_in[7];
  const float* g2  = (const float*)d_in[8];
  const float* be2 = (const float*)d_in[9];
  const float* Wfc = (const float*)d_in[10];
  const float* bfc = (const float*)d_in[11];
  float* out = (float*)d_out;

  char* ws = (char*)d_ws;
  size_t off = 0;
  auto alloc = [&](size_t bytes) {
    char* p = ws + off; off += (bytes + 255) & ~(size_t)255; return p;
  };
  unsigned short* ADJBF = (unsigned short*)alloc(512 * 512 * 2);
  unsigned short* ADJB  = (unsigned short*)alloc(512 * 512 * 2);
  unsigned short* W1T   = (unsigned short*)alloc(3 * 4096 * 2);
  unsigned short* W2T   = (unsigned short*)alloc(3 * 4096 * 2);
  float* SS1 = (float*)alloc(3 * 512 * 4);   // contiguous 4x6144B for one memset
  float* SQ1 = (float*)alloc(3 * 512 * 4);
  float* SS2 = (float*)alloc(3 * 512 * 4);
  float* SQ2 = (float*)alloc(3 * 512 * 4);
  float* A1  = (float*)alloc(3 * 512 * 4);
  float* C1  = (float*)alloc(3 * 512 * 4);
  float* RC  = (float*)alloc(512 * 4);
  float* SKIP = (float*)alloc(3 * 1024 * 64 * 4);
  float* OUTS = (float*)alloc(1024 * 192 * 4);
  unsigned short* XT  = (unsigned short*)alloc((size_t)1024 * 64 * 512 * 2);  // reused as H2T
  unsigned short* H1T = (unsigned short*)alloc((size_t)3 * 1024 * 64 * 512 * 2);
  unsigned short* H2T = XT;   // Xt dead after k_gnn1

  hipMemsetAsync(SS1, 0, 4 * 3 * 512 * 4, stream);

  k_prep_adj<<<1024, 256, 0, stream>>>(adj, ADJBF);
  k_prep_w<<<48, 256, 0, stream>>>(W1, W2, W1T, W2T);
  k_transpose_x<<<8192, 256, 0, stream>>>(X, XT);
  k_gnn1<<<2048, 512, 0, stream>>>(XT, ADJBF, W1T, b1, H1T, SS1, SQ1);

  for (int i = 0; i < 3; ++i) {
    k_adjb<<<512, 256, 0, stream>>>(ADJBF, SS1 + i * 512, SQ1 + i * 512,
                                    g1 + i * 512, be1 + i * 512, ADJB, RC,
                                    A1 + i * 512, C1 + i * 512);
    k_layer2<<<2048, 512, 0, stream>>>(H1T + (size_t)i * 33554432u, ADJB, RC,
                                       W2T + i * 4096, b2 + i * 64, H2T,
                                       SS2 + i * 512, SQ2 + i * 512,
                                       A1 + i * 512, C1 + i * 512, SKIP + i * 65536);
    k_minrow_out<<<16384, 256, 0, stream>>>(H2T, SS2 + i * 512, SQ2 + i * 512,
                                            g2 + i * 512, be2 + i * 512,
                                            SKIP + i * 65536, OUTS, i);
  }
  k_fc<<<128, 256, 0, stream>>>(OUTS, Wfc, bfc, out);
}